// Round 10
// baseline (916.059 us; speedup 1.0000x reference)
//
#include <hip/hip_runtime.h>
#include <hip/hip_cooperative_groups.h>
#include <math.h>

namespace cg = cooperative_groups;

// Problem constants
constexpr int NN = 50000;      // nodes
constexpr int NE = 800000;     // edges
constexpr int HD = 128;        // hidden
constexpr int NG = 10;         // groups
constexpr float LAM = 0.01f;
constexpr float EPSV = 1e-5f;
constexpr int NBLK = (NN + 255) / 256;     // 196 scan blocks
constexpr int GBLK = (NN + 63) / 64;       // 782 row-tile blocks
constexpr int NCOPY = 8;                   // stats atomic spread copies
constexpr int FGRID = 1024;                // frontend coop grid (4 blocks/CU)

typedef __attribute__((ext_vector_type(8))) short s8v;   // 8 bf16 (4 VGPRs)
typedef __attribute__((ext_vector_type(4))) float f4v;   // MFMA acc

// Shared-memory layout for the fused MFMA kernels (byte offsets):
//   As  [64*136] bf16 @ 0      (17408)
//   Ws  [128*136] bf16 @ 17408 (34816)  -> ends 52224
//   Ts  [64*136] bf16 @ 52224  (17408)  -> ends 69632
//   b1s @ 69632 | b2s @ 70144 | lws[128*11] @ 70656 | lbs @ 76288 | bcs @ 76352
//   overlays: combine cAs@0 (9216) cWs@9216 (18432);
//             apply ws_@0 mus_@5120 ks_@10240 ss_@10752 (ends 13312);
//             stats hF@0 (33792) sS@33792 (2560)
constexpr int SMEM_BYTES = 76864;

__device__ __forceinline__ float softplus_f(float x) {
    return fmaxf(x, 0.f) + log1pf(expf(-fabsf(x)));
}
__device__ __forceinline__ unsigned short f2b(float f) {
    unsigned u = __float_as_uint(f);
    unsigned r = (u + 0x7FFFu + ((u >> 16) & 1u)) >> 16;
    return (unsigned short)r;
}
__device__ __forceinline__ float b2f(unsigned short u) {
    return __uint_as_float(((unsigned)u) << 16);
}

// ======== cooperative frontend: zero+prep+xconv | hist | scan1 | scan3 |
//          fill | gather — one launch, grid.sync between phases ==============
__global__ __launch_bounds__(256) void frontend_kernel(
    const int* __restrict__ rows,
    int* __restrict__ zbase, int zcount,
    int* __restrict__ cnt, int* __restrict__ bsum,
    int* __restrict__ off, int* __restrict__ cur, int* __restrict__ eid,
    const float* __restrict__ ef, uint4* __restrict__ msgbf,
    const float* __restrict__ x, unsigned short* __restrict__ xbf,
    const float* __restrict__ Wc,
    const float* __restrict__ W1a, const float* __restrict__ W2a,
    const float* __restrict__ W1b, const float* __restrict__ W2b,
    short* __restrict__ wct, short* __restrict__ wts)
{
    cg::grid_group grid = cg::this_grid();
    __shared__ int sA[256];
    __shared__ int sB[256];
    __shared__ int basev;
    const int t = threadIdx.x;
    const int gtid = blockIdx.x * 256 + t;
    const int nthr = gridDim.x * 256;

    // ---- phase 0: zero cnt+sums; weights -> bf16 transposed; x -> bf16 ----
    for (int i = gtid; i < zcount; i += nthr) zbase[i] = 0;
    for (int i = gtid; i < 40960; i += nthr) {
        int n = i / 320, kk = i % 320;
        wct[i] = (short)f2b(Wc[kk * 128 + n]);
    }
    for (int j = gtid; j < 65536; j += nthr) {
        int mat = j >> 14, idx = j & 16383;
        int n = idx >> 7, kk = idx & 127;
        const float* src = (mat == 0) ? W1a : (mat == 1) ? W2a
                         : (mat == 2) ? W1b : W2b;
        wts[j] = (short)f2b(src[kk * 128 + n]);
    }
    for (int i = gtid; i < NN * 32; i += nthr) {   // NN*128 floats, x4 at a time
        float4 v = reinterpret_cast<const float4*>(x)[i];
        ushort4 o;
        o.x = f2b(v.x); o.y = f2b(v.y); o.z = f2b(v.z); o.w = f2b(v.w);
        reinterpret_cast<ushort4*>(xbf)[i] = o;
    }
    grid.sync();

    // ---- phase 1: histogram (int4 reads) ----
    for (int i = gtid; i < NE / 4; i += nthr) {
        int4 r = reinterpret_cast<const int4*>(rows)[i];
        atomicAdd(&cnt[r.x], 1);
        atomicAdd(&cnt[r.y], 1);
        atomicAdd(&cnt[r.z], 1);
        atomicAdd(&cnt[r.w], 1);
    }
    grid.sync();

    // ---- phase 2: per-block sums ----
    if ((int)blockIdx.x < NBLK) {
        int i = blockIdx.x * 256 + t;
        sA[t] = (i < NN) ? cnt[i] : 0;
        __syncthreads();
        for (int d = 128; d > 0; d >>= 1) {
            if (t < d) sA[t] += sA[t + d];
            __syncthreads();
        }
        if (t == 0) bsum[blockIdx.x] = sA[0];
    }
    grid.sync();

    // ---- phase 3: final offsets (every scan block rescans the 196 partials) --
    if ((int)blockIdx.x < NBLK) {
        int i = blockIdx.x * 256 + t;
        int v  = (i < NN) ? cnt[i] : 0;
        int bv = (t < NBLK) ? bsum[t] : 0;
        sA[t] = v; sB[t] = bv;
        __syncthreads();
        for (int d = 1; d < 256; d <<= 1) {
            int u1 = (t >= d) ? sA[t - d] : 0;
            int u2 = (t >= d) ? sB[t - d] : 0;
            __syncthreads();
            sA[t] += u1; sB[t] += u2;
            __syncthreads();
        }
        if (t == (int)blockIdx.x) basev = sB[t] - bv;
        __syncthreads();
        int excl = sA[t] - v + basev;
        if (i < NN) { off[i] = excl; cur[i] = excl; }
        if (i == NN - 1) off[NN] = NE;
    }
    grid.sync();

    // ---- phase 4: bucket fill ----
    for (int i = gtid; i < NE / 4; i += nthr) {
        int4 r = reinterpret_cast<const int4*>(rows)[i];
        int base = i * 4;
        eid[atomicAdd(&cur[r.x], 1)] = base + 0;
        eid[atomicAdd(&cur[r.y], 1)] = base + 1;
        eid[atomicAdd(&cur[r.z], 1)] = base + 2;
        eid[atomicAdd(&cur[r.w], 1)] = base + 3;
    }
    grid.sync();

    // ---- phase 5: gather (1 wave/node; 16 lanes x 32B, 4 edges in flight) ----
    const int wv = t >> 6, lane = t & 63;
    const int eg = lane >> 4, lc = lane & 15;
    for (int ng = blockIdx.x; ng * 4 < NN; ng += gridDim.x) {
        int node = ng * 4 + wv;
        if (node >= NN) continue;
        int b = off[node], e = off[node + 1];
        float acc[8];
        #pragma unroll
        for (int j = 0; j < 8; ++j) acc[j] = 0.f;
        for (int i = b + eg; i < e; i += 4) {
            int ed = eid[i];
            const float* src = ef + (size_t)ed * HD + lc * 8;
            float4 v0 = *reinterpret_cast<const float4*>(src);
            float4 v1 = *reinterpret_cast<const float4*>(src + 4);
            acc[0] += v0.x; acc[1] += v0.y; acc[2] += v0.z; acc[3] += v0.w;
            acc[4] += v1.x; acc[5] += v1.y; acc[6] += v1.z; acc[7] += v1.w;
        }
        #pragma unroll
        for (int j = 0; j < 8; ++j) {
            acc[j] += __shfl_xor(acc[j], 16);
            acc[j] += __shfl_xor(acc[j], 32);
        }
        if (eg == 0) {
            uint4 pk;
            pk.x = (unsigned)f2b(acc[0]) | ((unsigned)f2b(acc[1]) << 16);
            pk.y = (unsigned)f2b(acc[2]) | ((unsigned)f2b(acc[3]) << 16);
            pk.z = (unsigned)f2b(acc[4]) | ((unsigned)f2b(acc[5]) << 16);
            pk.w = (unsigned)f2b(acc[6]) | ((unsigned)f2b(acc[7]) << 16);
            msgbf[(size_t)node * 16 + lc] = pk;
        }
    }
}

// ---- fused12 tail: assumes As (A-tile bf16) + Ws (W1t) staged & synced,
//      b1s/b2s/lws/lbs loaded. Computes h, s, writes hbf/sout, atomics stats. --
__device__ __forceinline__ void fused12_tail(
    char* smem, const short* __restrict__ w2t,
    unsigned short* __restrict__ hbf, float* __restrict__ sout,
    float* __restrict__ sums_base, int m0)
{
    short* As = (short*)(smem);
    short* Ws = (short*)(smem + 17408);
    short* Ts = (short*)(smem + 52224);
    float* b1s = (float*)(smem + 69632);
    float* b2s = (float*)(smem + 70144);
    float* lws = (float*)(smem + 70656);
    float* lbs = (float*)(smem + 76288);
    float* hF = (float*)(smem);            // stats overlay
    float* sS = (float*)(smem + 33792);    // stats overlay

    const int tid = threadIdx.x;
    const int lane = tid & 63;
    const int wv = tid >> 6;
    const int fr = lane & 15;
    const int fc = lane >> 4;

    f4v acc[8];
    #pragma unroll
    for (int ct = 0; ct < 8; ++ct) acc[ct] = (f4v){0.f, 0.f, 0.f, 0.f};
    {
        const short* ap = As + (wv * 16 + fr) * 136 + fc * 8;
        const short* bp = Ws + fr * 136 + fc * 8;
        #pragma unroll
        for (int ks = 0; ks < 4; ++ks) {
            s8v a = *(const s8v*)(ap + ks * 32);
            #pragma unroll
            for (int ct = 0; ct < 8; ++ct) {
                s8v b = *(const s8v*)(bp + ct * 16 * 136 + ks * 32);
                acc[ct] = __builtin_amdgcn_mfma_f32_16x16x32_bf16(a, b, acc[ct], 0, 0, 0);
            }
        }
    }
    // t = softplus(.+b1) -> Ts bf16
    {
        int rb = wv * 16 + fc * 4;
        #pragma unroll
        for (int ct = 0; ct < 8; ++ct) {
            int col = ct * 16 + fr;
            float bv = b1s[col];
            #pragma unroll
            for (int r = 0; r < 4; ++r)
                Ts[(rb + r) * 136 + col] = (short)f2b(softplus_f(acc[ct][r] + bv));
        }
    }
    __syncthreads();
    // stage W2t over Ws
    {
        int col = tid >> 1, seg = (tid & 1) * 64;
        const short* src = w2t + (size_t)col * 128 + seg;
        #pragma unroll
        for (int j = 0; j < 8; ++j)
            *(s8v*)&Ws[col * 136 + seg + 8 * j] = *(const s8v*)(src + 8 * j);
    }
    __syncthreads();

    #pragma unroll
    for (int ct = 0; ct < 8; ++ct) acc[ct] = (f4v){0.f, 0.f, 0.f, 0.f};
    {
        const short* ap = Ts + (wv * 16 + fr) * 136 + fc * 8;
        const short* bp = Ws + fr * 136 + fc * 8;
        #pragma unroll
        for (int ks = 0; ks < 4; ++ks) {
            s8v a = *(const s8v*)(ap + ks * 32);
            #pragma unroll
            for (int ct = 0; ct < 8; ++ct) {
                s8v b = *(const s8v*)(bp + ct * 16 * 136 + ks * 32);
                acc[ct] = __builtin_amdgcn_mfma_f32_16x16x32_bf16(a, b, acc[ct], 0, 0, 0);
            }
        }
    }
    // h = acc + b2
    #pragma unroll
    for (int ct = 0; ct < 8; ++ct) {
        float bv = b2s[ct * 16 + fr];
        #pragma unroll
        for (int r = 0; r < 4; ++r) acc[ct][r] += bv;
    }
    // s = softmax(h @ linW + linb) via 16-lane butterfly
    float dot[4][10];
    #pragma unroll
    for (int r = 0; r < 4; ++r)
        #pragma unroll
        for (int g = 0; g < 10; ++g) dot[r][g] = 0.f;
    #pragma unroll
    for (int ct = 0; ct < 8; ++ct) {
        #pragma unroll
        for (int g = 0; g < 10; ++g) {
            float lwv = lws[(ct * 16 + fr) * 11 + g];
            #pragma unroll
            for (int r = 0; r < 4; ++r) dot[r][g] += acc[ct][r] * lwv;
        }
    }
    #pragma unroll
    for (int r = 0; r < 4; ++r)
        #pragma unroll
        for (int g = 0; g < 10; ++g) {
            float v = dot[r][g];
            v += __shfl_xor(v, 1);
            v += __shfl_xor(v, 2);
            v += __shfl_xor(v, 4);
            v += __shfl_xor(v, 8);
            dot[r][g] = v + lbs[g];
        }
    #pragma unroll
    for (int r = 0; r < 4; ++r) {
        float m = dot[r][0];
        #pragma unroll
        for (int g = 1; g < 10; ++g) m = fmaxf(m, dot[r][g]);
        float sum = 0.f;
        #pragma unroll
        for (int g = 0; g < 10; ++g) { dot[r][g] = expf(dot[r][g] - m); sum += dot[r][g]; }
        float inv = 1.f / sum;
        #pragma unroll
        for (int g = 0; g < 10; ++g) dot[r][g] *= inv;
    }
    const int growb = m0 + wv * 16 + fc * 4;
    const int rlocb = wv * 16 + fc * 4;
    unsigned short hq[8][4];
    #pragma unroll
    for (int ct = 0; ct < 8; ++ct) {
        int col = ct * 16 + fr;
        #pragma unroll
        for (int r = 0; r < 4; ++r) {
            hq[ct][r] = f2b(acc[ct][r]);
            int row = growb + r;
            if (row < NN) hbf[(size_t)row * 128 + col] = hq[ct][r];
        }
    }
    if (fr < 10) {
        #pragma unroll
        for (int r = 0; r < 4; ++r) {
            int row = growb + r;
            if (row < NN) {
                float v = 0.f;
                #pragma unroll
                for (int g = 0; g < 10; ++g) v = (fr == g) ? dot[r][g] : v;
                sout[(size_t)row * 10 + fr] = v;
            }
        }
    }
    // block-local stats -> atomics into one of NCOPY spread copies
    __syncthreads();   // all waves done with As/Ws/Ts
    #pragma unroll
    for (int ct = 0; ct < 8; ++ct) {
        int col = ct * 16 + fr;
        #pragma unroll
        for (int r = 0; r < 4; ++r) {
            bool valid = (growb + r) < NN;
            hF[(rlocb + r) * 132 + col] = valid ? b2f(hq[ct][r]) : 0.f;
        }
    }
    if (fr < 10) {
        #pragma unroll
        for (int r = 0; r < 4; ++r) {
            bool valid = (growb + r) < NN;
            float v = 0.f;
            #pragma unroll
            for (int g = 0; g < 10; ++g) v = (fr == g) ? dot[r][g] : v;
            sS[(rlocb + r) * 10 + fr] = valid ? v : 0.f;
        }
    }
    __syncthreads();
    {
        float* sums = sums_base + (size_t)(blockIdx.x & (NCOPY - 1)) * 2560;
        const int c = tid & 127;
        const int g0 = (tid >> 7) * 5;
        float a1[5], a2[5];
        #pragma unroll
        for (int q = 0; q < 5; ++q) { a1[q] = 0.f; a2[q] = 0.f; }
        for (int n = 0; n < 64; ++n) {
            float hv = hF[n * 132 + c];
            #pragma unroll
            for (int q = 0; q < 5; ++q) {
                float pv = sS[n * 10 + g0 + q] * hv;
                a1[q] += pv;
                a2[q] += pv * pv;
            }
        }
        #pragma unroll
        for (int q = 0; q < 5; ++q) {
            atomicAdd(&sums[(g0 + q) * 128 + c], a1[q]);
            atomicAdd(&sums[1280 + (g0 + q) * 128 + c], a2[q]);
        }
    }
}

// ---- kernel: combine (K=320 MFMA, bf16 inputs) + fused12 block a -------------
__global__ __launch_bounds__(256) void combine_f12a_kernel(
    const unsigned short* __restrict__ xbf, const short* __restrict__ msgbf,
    const float* __restrict__ gf, const short* __restrict__ wct,
    const float* __restrict__ bc,
    const short* __restrict__ w1t, const short* __restrict__ w2t,
    const float* __restrict__ b1, const float* __restrict__ b2,
    const float* __restrict__ linW, const float* __restrict__ linb,
    unsigned short* __restrict__ out0bf, unsigned short* __restrict__ hbf,
    float* __restrict__ sout, float* __restrict__ sums)
{
    __shared__ __align__(16) char smem[SMEM_BYTES];
    short* cAs = (short*)(smem);            // combine A: 64x72 bf16
    short* cWs = (short*)(smem + 9216);     // combine W: 128x72 bf16
    short* As  = (short*)(smem);
    short* Ws  = (short*)(smem + 17408);
    float* b1s = (float*)(smem + 69632);
    float* b2s = (float*)(smem + 70144);
    float* lws = (float*)(smem + 70656);
    float* lbs = (float*)(smem + 76288);
    float* bcs = (float*)(smem + 76352);

    const int tid = threadIdx.x;
    const int m0 = blockIdx.x * 64;
    if (tid < 128) { bcs[tid] = bc[tid]; b1s[tid] = b1[tid]; b2s[tid] = b2[tid]; }
    for (int i = tid; i < 1280; i += 256) lws[(i / 10) * 11 + (i % 10)] = linW[i];
    if (tid < 10) lbs[tid] = linb[tid];
    const int lane = tid & 63;
    const int wv = tid >> 6;
    const int fr = lane & 15;
    const int fc = lane >> 4;

    f4v acc[8];
    #pragma unroll
    for (int ct = 0; ct < 8; ++ct) acc[ct] = (f4v){0.f, 0.f, 0.f, 0.f};

    const int arow = tid >> 2;
    const int aseg = (tid & 3) * 16;
    const int wcol = tid >> 1;
    const int wseg = (tid & 1) * 32;

    for (int c = 0; c < 5; ++c) {
        const int k0 = c * 64;
        {
            short tmp[16];
            int grow = m0 + arow;
            if (grow >= NN) {
                #pragma unroll
                for (int j = 0; j < 16; ++j) tmp[j] = 0;
            } else if (c < 2) {
                const short* src = (const short*)xbf + (size_t)grow * 128 + k0 + aseg;
                *(s8v*)tmp = *(const s8v*)src;
                *(s8v*)(tmp + 8) = *(const s8v*)(src + 8);
            } else if (c < 4) {
                const short* src = msgbf + (size_t)grow * 128 + (k0 - 128) + aseg;
                *(s8v*)tmp = *(const s8v*)src;
                *(s8v*)(tmp + 8) = *(const s8v*)(src + 8);
            } else {
                const float* src = gf + aseg;
                #pragma unroll
                for (int q = 0; q < 4; ++q) {
                    float4 v = *reinterpret_cast<const float4*>(src + 4 * q);
                    tmp[4*q+0] = (short)f2b(v.x); tmp[4*q+1] = (short)f2b(v.y);
                    tmp[4*q+2] = (short)f2b(v.z); tmp[4*q+3] = (short)f2b(v.w);
                }
            }
            *(s8v*)&cAs[arow * 72 + aseg] = *(s8v*)tmp;
            *(s8v*)&cAs[arow * 72 + aseg + 8] = *(s8v*)(tmp + 8);
        }
        {
            const short* src = wct + (size_t)wcol * 320 + k0 + wseg;
            #pragma unroll
            for (int j = 0; j < 4; ++j)
                *(s8v*)&cWs[wcol * 72 + wseg + 8 * j] = *(const s8v*)(src + 8 * j);
        }
        __syncthreads();
        const short* ap = cAs + (wv * 16 + fr) * 72 + fc * 8;
        const short* bp = cWs + fr * 72 + fc * 8;
        #pragma unroll
        for (int ks = 0; ks < 2; ++ks) {
            s8v a = *(const s8v*)(ap + ks * 32);
            #pragma unroll
            for (int ct = 0; ct < 8; ++ct) {
                s8v b = *(const s8v*)(bp + ct * 16 * 72 + ks * 32);
                acc[ct] = __builtin_amdgcn_mfma_f32_16x16x32_bf16(a, b, acc[ct], 0, 0, 0);
            }
        }
        __syncthreads();   // staging buffers free after this
    }
    // epilogue: out0 = softplus(acc + bc); write global + LDS A-tile for fused12
    const int rbase = m0 + wv * 16 + fc * 4;
    const int rloc  = wv * 16 + fc * 4;
    #pragma unroll
    for (int ct = 0; ct < 8; ++ct) {
        int col = ct * 16 + fr;
        float bv = bcs[col];
        #pragma unroll
        for (int r = 0; r < 4; ++r) {
            unsigned short q = f2b(softplus_f(acc[ct][r] + bv));
            bool valid = (rbase + r) < NN;
            if (valid) out0bf[(size_t)(rbase + r) * 128 + col] = q;
            As[(rloc + r) * 136 + col] = valid ? (short)q : (short)0;
        }
    }
    // stage W1t
    {
        int col = tid >> 1, seg = (tid & 1) * 64;
        const short* src = w1t + (size_t)col * 128 + seg;
        #pragma unroll
        for (int j = 0; j < 8; ++j)
            *(s8v*)&Ws[col * 136 + seg + 8 * j] = *(const s8v*)(src + 8 * j);
    }
    __syncthreads();
    fused12_tail(smem, w2t, hbf, sout, sums, m0);
}

// ---- kernel: apply block a (inline finalize, 8-copy merge) + fused12 block b -
__global__ __launch_bounds__(256) void apply_f12b_kernel(
    const unsigned short* __restrict__ out0bf,
    const float* __restrict__ sums_a,
    const float* __restrict__ gamma_a, const float* __restrict__ beta_a,
    const short* __restrict__ w1t, const short* __restrict__ w2t,
    const float* __restrict__ b1, const float* __restrict__ b2,
    const float* __restrict__ linW, const float* __restrict__ linb,
    unsigned short* __restrict__ out1bf,
    unsigned short* __restrict__ hbf,     // in: h_a rows (own tile); out: h_b
    float* __restrict__ sout,             // in: s_a rows (own tile); out: s_b
    float* __restrict__ sums_b)
{
    __shared__ __align__(16) char smem[SMEM_BYTES];
    float* ws_  = (float*)(smem);            // 1280
    float* mus_ = (float*)(smem + 5120);     // 1280
    float* ks_  = (float*)(smem + 10240);    // 128
    float* ss_  = (float*)(smem + 10752);    // 640
    short* As   = (short*)(smem);
    short* Ws   = (short*)(smem + 17408);
    float* b1s  = (float*)(smem + 69632);
    float* b2s  = (float*)(smem + 70144);
    float* lws  = (float*)(smem + 70656);
    float* lbs  = (float*)(smem + 76288);

    const int tid = threadIdx.x;
    const int m0 = blockIdx.x * 64;
    if (tid < 128) { b1s[tid] = b1[tid]; b2s[tid] = b2[tid]; }
    for (int i = tid; i < 1280; i += 256) lws[(i / 10) * 11 + (i % 10)] = linW[i];
    if (tid < 10) lbs[tid] = linb[tid];
    const float invn = 1.f / (float)NN;
    for (int idx = tid; idx < 1280; idx += 256) {
        float s1 = 0.f, s2 = 0.f;
        #pragma unroll
        for (int k = 0; k < NCOPY; ++k) {
            s1 += sums_a[(size_t)k * 2560 + idx];
            s2 += sums_a[(size_t)k * 2560 + idx + 1280];
        }
        float mu = s1 * invn;
        float var = s2 * invn - mu * mu;
        float wg = rsqrtf(var + EPSV) * gamma_a[idx];
        ws_[idx] = wg;
        mus_[idx] = mu;
    }
    for (int i = tid; i < 640; i += 256) {
        int n = m0 + i / 10;
        ss_[i] = (n < NN) ? sout[(size_t)n * 10 + i % 10] : 0.f;
    }
    // stage W1t (disjoint LDS region; overlaps nothing in phase A)
    {
        int col = tid >> 1, seg = (tid & 1) * 64;
        const short* src = w1t + (size_t)col * 128 + seg;
        #pragma unroll
        for (int j = 0; j < 8; ++j)
            *(s8v*)&Ws[col * 136 + seg + 8 * j] = *(const s8v*)(src + 8 * j);
    }
    __syncthreads();
    if (tid < 128) {
        float kacc = 0.f;
        #pragma unroll
        for (int g = 0; g < NG; ++g) {
            int idx = g * 128 + tid;
            kacc += beta_a[idx] - mus_[idx] * ws_[idx];
        }
        ks_[tid] = kacc;
    }
    __syncthreads();
    // apply math: out1 = out0 + h + LAM*(h*A + K); keep bf16 vals for A-tile
    const int tc = tid & 31, rg = tid >> 5;
    ushort4 vals[8];
    #pragma unroll
    for (int p = 0; p < 8; ++p) {
        int nl = p * 8 + rg;
        int n = m0 + nl;
        if (n >= NN) { vals[p].x = vals[p].y = vals[p].z = vals[p].w = 0; continue; }
        float A0 = 0.f, A1 = 0.f, A2 = 0.f, A3 = 0.f;
        #pragma unroll
        for (int g = 0; g < 10; ++g) {
            float sv = ss_[nl * 10 + g];
            float4 wv4 = *reinterpret_cast<const float4*>(&ws_[g * 128 + tc * 4]);
            A0 += sv * wv4.x; A1 += sv * wv4.y; A2 += sv * wv4.z; A3 += sv * wv4.w;
        }
        ushort4 hv4 = *reinterpret_cast<const ushort4*>(hbf + (size_t)n * 128 + tc * 4);
        ushort4 ov4 = *reinterpret_cast<const ushort4*>(out0bf + (size_t)n * 128 + tc * 4);
        float h0 = b2f(hv4.x), h1 = b2f(hv4.y), h2 = b2f(hv4.z), h3 = b2f(hv4.w);
        float r0 = b2f(ov4.x) + h0 + LAM * (h0 * A0 + ks_[tc * 4 + 0]);
        float r1 = b2f(ov4.y) + h1 + LAM * (h1 * A1 + ks_[tc * 4 + 1]);
        float r2 = b2f(ov4.z) + h2 + LAM * (h2 * A2 + ks_[tc * 4 + 2]);
        float r3 = b2f(ov4.w) + h3 + LAM * (h3 * A3 + ks_[tc * 4 + 3]);
        ushort4 o;
        o.x = f2b(r0); o.y = f2b(r1); o.z = f2b(r2); o.w = f2b(r3);
        *reinterpret_cast<ushort4*>(out1bf + (size_t)n * 128 + tc * 4) = o;
        vals[p] = o;
    }
    __syncthreads();   // phase-A LDS reads complete
    // write A-tile for fused12_b
    #pragma unroll
    for (int p = 0; p < 8; ++p) {
        int row = p * 8 + rg;
        *reinterpret_cast<ushort4*>(&As[row * 136 + tc * 4]) = vals[p];
    }
    __syncthreads();
    fused12_tail(smem, w2t, hbf, sout, sums_b, m0);
}

// -------------------- apply last: out = out1 + h_b + DGN + initial ------------
__global__ __launch_bounds__(256) void apply_last_kernel(
    const unsigned short* __restrict__ out1bf,
    const unsigned short* __restrict__ hbf,
    const float* __restrict__ s, const float* __restrict__ sums,
    const float* __restrict__ gamma, const float* __restrict__ beta,
    const unsigned short* __restrict__ out0bf,
    float* __restrict__ dstf)
{
    __shared__ __align__(16) float ws_[1280];
    __shared__ float mus_[1280];
    __shared__ float ks_[128];
    __shared__ float ss_[640];
    const int tid = threadIdx.x;
    const int m0 = blockIdx.x * 64;
    const float invn = 1.f / (float)NN;
    for (int idx = tid; idx < 1280; idx += 256) {
        float s1 = 0.f, s2 = 0.f;
        #pragma unroll
        for (int k = 0; k < NCOPY; ++k) {
            s1 += sums[(size_t)k * 2560 + idx];
            s2 += sums[(size_t)k * 2560 + idx + 1280];
        }
        float mu = s1 * invn;
        float var = s2 * invn - mu * mu;
        float wg = rsqrtf(var + EPSV) * gamma[idx];
        ws_[idx] = wg;
        mus_[idx] = mu;
    }
    for (int i = tid; i < 640; i += 256) {
        int n = m0 + i / 10;
        ss_[i] = (n < NN) ? s[(size_t)n * 10 + i % 10] : 0.f;
    }
    __syncthreads();
    if (tid < 128) {
        float kacc = 0.f;
        #pragma unroll
        for (int g = 0; g < NG; ++g) {
            int idx = g * 128 + tid;
            kacc += beta[idx] - mus_[idx] * ws_[idx];
        }
        ks_[tid] = kacc;
    }
    __syncthreads();
    const int tc = tid & 31, rg = tid >> 5;
    #pragma unroll
    for (int p = 0; p < 8; ++p) {
        int nl = p * 8 + rg;
        int n = m0 + nl;
        if (n >= NN) continue;
        float A0 = 0.f, A1 = 0.f, A2 = 0.f, A3 = 0.f;
        #pragma unroll
        for (int g = 0; g < 10; ++g) {
            float sv = ss_[nl * 10 + g];
            float4 wv4 = *reinterpret_cast<const float4*>(&ws_[g * 128 + tc * 4]);
            A0 += sv * wv4.x; A1 += sv * wv4.y; A2 += sv * wv4.z; A3 += sv * wv4.w;
        }
        ushort4 hv4 = *reinterpret_cast<const ushort4*>(hbf + (size_t)n * 128 + tc * 4);
        ushort4 ov4 = *reinterpret_cast<const ushort4*>(out1bf + (size_t)n * 128 + tc * 4);
        ushort4 iv4 = *reinterpret_cast<const ushort4*>(out0bf + (size_t)n * 128 + tc * 4);
        float h0 = b2f(hv4.x), h1 = b2f(hv4.y), h2 = b2f(hv4.z), h3 = b2f(hv4.w);
        float r0 = b2f(ov4.x) + h0 + LAM * (h0 * A0 + ks_[tc * 4 + 0]) + b2f(iv4.x);
        float r1 = b2f(ov4.y) + h1 + LAM * (h1 * A1 + ks_[tc * 4 + 1]) + b2f(iv4.y);
        float r2 = b2f(ov4.z) + h2 + LAM * (h2 * A2 + ks_[tc * 4 + 2]) + b2f(iv4.z);
        float r3 = b2f(ov4.w) + h3 + LAM * (h3 * A3 + ks_[tc * 4 + 3]) + b2f(iv4.w);
        *reinterpret_cast<float4*>(dstf + (size_t)n * 128 + tc * 4) =
            make_float4(r0, r1, r2, r3);
    }
}

// ------------------------------------------------------------------------------
extern "C" void kernel_launch(void* const* d_in, const int* in_sizes, int n_in,
                              void* d_out, int out_size, void* d_ws, size_t ws_size,
                              hipStream_t stream)
{
    const float* x    = (const float*)d_in[0];
    const int*   eidx = (const int*)  d_in[1];
    const float* ef   = (const float*)d_in[2];
    const float* gf   = (const float*)d_in[3];
    const float* Wc   = (const float*)d_in[4];
    const float* bc   = (const float*)d_in[5];

    float* p = (float*)d_ws;
    // zero region handled by frontend phase 0: [cnt NN][sums_a][sums_b]
    int*   cnt    = (int*)p;                      p += NN;
    float* sums_a = p;                            p += (size_t)NCOPY * 2560;
    float* sums_b = p;                            p += (size_t)NCOPY * 2560;
    unsigned short* msgbf  = (unsigned short*)p;  p += (size_t)NN * 64;
    unsigned short* out0bf = (unsigned short*)p;  p += (size_t)NN * 64;
    unsigned short* out1bf = (unsigned short*)p;  p += (size_t)NN * 64;
    unsigned short* hbf    = (unsigned short*)p;  p += (size_t)NN * 64;
    unsigned short* xbf    = (unsigned short*)p;  p += (size_t)NN * 64;
    float* sbuf = p;                              p += (size_t)NN * 10;
    short* wct  = (short*)p;                      // 40960 shorts
    short* wts  = wct + 40960;                    // 4*16384 shorts

    // CSR scratch aliased into buffers written later:
    int* off   = (int*)out1bf;           // NN+1  (out1bf written in apply_f12b)
    int* cur   = off + NN + 1;           // NN
    int* bsum  = cur + NN;               // NBLK
    int* eid   = (int*)hbf;              // NE    (hbf written in combine_f12a)

    const int zcount = NN + 2 * NCOPY * 2560;

    // ---- cooperative frontend: zero+prep+xconv | hist | scan | fill | gather -
    {
        const int* rows = eidx;
        int* zbase = cnt;
        int zc = zcount;
        uint4* msg4 = (uint4*)msgbf;
        const float* W1a = (const float*)d_in[6];
        const float* W2a = (const float*)d_in[8];
        const float* W1b = (const float*)d_in[14];
        const float* W2b = (const float*)d_in[16];
        void* args[] = {
            (void*)&rows, (void*)&zbase, (void*)&zc,
            (void*)&cnt, (void*)&bsum, (void*)&off, (void*)&cur, (void*)&eid,
            (void*)&ef, (void*)&msg4, (void*)&x, (void*)&xbf,
            (void*)&Wc, (void*)&W1a, (void*)&W2a, (void*)&W1b, (void*)&W2b,
            (void*)&wct, (void*)&wts
        };
        hipLaunchCooperativeKernel((void*)frontend_kernel, dim3(FGRID), dim3(256),
                                   args, 0, stream);
    }

    const short* w1ta = wts;
    const short* w2ta = wts + 16384;
    const short* w1tb = wts + 32768;
    const short* w2tb = wts + 49152;

    // combine + block a (writes out0bf, h_a, s_a; atomics sums_a copies)
    combine_f12a_kernel<<<GBLK, 256, 0, stream>>>(
        xbf, (const short*)msgbf, gf, wct, bc,
        w1ta, w2ta, (const float*)d_in[7], (const float*)d_in[9],
        (const float*)d_in[10], (const float*)d_in[11],
        out0bf, hbf, sbuf, sums_a);

    // apply_a + block b (merges sums_a copies; writes out1bf, h_b, s_b)
    apply_f12b_kernel<<<GBLK, 256, 0, stream>>>(
        out0bf, sums_a, (const float*)d_in[12], (const float*)d_in[13],
        w1tb, w2tb, (const float*)d_in[15], (const float*)d_in[17],
        (const float*)d_in[18], (const float*)d_in[19],
        out1bf, hbf, sbuf, sums_b);

    // final apply: d_out = out1 + h_b + DGN_b + initial(out0)
    apply_last_kernel<<<GBLK, 256, 0, stream>>>(
        out1bf, hbf, sbuf, sums_b, (const float*)d_in[20], (const float*)d_in[21],
        out0bf, (float*)d_out);
}

// Round 11
// 397.826 us; speedup vs baseline: 2.3027x; 2.3027x over previous
//
#include <hip/hip_runtime.h>
#include <math.h>

// Problem constants
constexpr int NN = 50000;      // nodes
constexpr int NE = 800000;     // edges
constexpr int HD = 128;        // hidden
constexpr int NG = 10;         // groups
constexpr float LAM = 0.01f;
constexpr float EPSV = 1e-5f;
constexpr int NBLK = (NN + 255) / 256;     // 196 scan blocks
constexpr int GBLK = (NN + 63) / 64;       // 782 row-tile blocks
constexpr int NCOPY = 8;                   // stats atomic spread copies

typedef __attribute__((ext_vector_type(8))) short s8v;   // 8 bf16 (4 VGPRs)
typedef __attribute__((ext_vector_type(4))) float f4v;   // MFMA acc

constexpr int SMEM_BYTES = 76864;

__device__ __forceinline__ float softplus_f(float x) {
    return fmaxf(x, 0.f) + log1pf(expf(-fabsf(x)));
}
__device__ __forceinline__ unsigned short f2b(float f) {
    unsigned u = __float_as_uint(f);
    unsigned r = (u + 0x7FFFu + ((u >> 16) & 1u)) >> 16;
    return (unsigned short)r;
}
__device__ __forceinline__ float b2f(unsigned short u) {
    return __uint_as_float(((unsigned)u) << 16);
}

// ------ hist (int4 reads) + weight prep + x->bf16, disjoint block ranges ------
constexpr int EBLOCKS = (NE / 4 + 255) / 256;            // 782
constexpr int PBLOCKS = 416;                             // weight prep
constexpr int XBLOCKS = (NN * 32 + 255) / 256;           // 6250 (x convert, f4)
__global__ __launch_bounds__(256) void hist_prep_kernel(
    const int* __restrict__ rows, int* __restrict__ cnt,
    const float* __restrict__ Wc,
    const float* __restrict__ W1a, const float* __restrict__ W2a,
    const float* __restrict__ W1b, const float* __restrict__ W2b,
    short* __restrict__ wct, short* __restrict__ wts,
    const float* __restrict__ x, unsigned short* __restrict__ xbf)
{
    int bid = blockIdx.x;
    if (bid < EBLOCKS) {
        int base = (bid * 256 + threadIdx.x) * 4;
        if (base < NE) {   // NE % 4 == 0
            int4 r = *reinterpret_cast<const int4*>(rows + base);
            atomicAdd(&cnt[r.x], 1);
            atomicAdd(&cnt[r.y], 1);
            atomicAdd(&cnt[r.z], 1);
            atomicAdd(&cnt[r.w], 1);
        }
    } else if (bid < EBLOCKS + PBLOCKS) {
        int i = (bid - EBLOCKS) * 256 + threadIdx.x;
        if (i < 40960) {
            int n = i / 320, kk = i % 320;
            wct[i] = (short)f2b(Wc[kk * 128 + n]);
        } else if (i < 40960 + 4 * 16384) {
            int j = i - 40960;
            int mat = j >> 14;
            int idx = j & 16383;
            int n = idx >> 7, kk = idx & 127;
            const float* src = (mat == 0) ? W1a : (mat == 1) ? W2a
                             : (mat == 2) ? W1b : W2b;
            wts[j] = (short)f2b(src[kk * 128 + n]);
        }
    } else {
        int i = (bid - EBLOCKS - PBLOCKS) * 256 + threadIdx.x;
        if (i < NN * 32) {
            float4 v = reinterpret_cast<const float4*>(x)[i];
            ushort4 o;
            o.x = f2b(v.x); o.y = f2b(v.y); o.z = f2b(v.z); o.w = f2b(v.w);
            reinterpret_cast<ushort4*>(xbf)[i] = o;
        }
    }
}

// -------------------- scan stage 1: per-block sums ----------------------------
__global__ __launch_bounds__(256) void scan1_kernel(
    const int* __restrict__ cnt, int* __restrict__ bsum)
{
    __shared__ int red[256];
    int t = threadIdx.x;
    int i = blockIdx.x * 256 + t;
    red[t] = (i < NN) ? cnt[i] : 0;
    __syncthreads();
    for (int d = 128; d > 0; d >>= 1) {
        if (t < d) red[t] += red[t + d];
        __syncthreads();
    }
    if (t == 0) bsum[blockIdx.x] = red[0];
}

// ------ scan stage 2+3 merged: every block scans the 196 partials in LDS ------
__global__ __launch_bounds__(256) void scan3_kernel(
    const int* __restrict__ cnt, const int* __restrict__ bsum,
    int* __restrict__ off, int* __restrict__ cur)
{
    __shared__ int sh[256];
    __shared__ int bs[256];
    __shared__ int basev;
    int t = threadIdx.x;
    int i = blockIdx.x * 256 + t;
    int v  = (i < NN) ? cnt[i] : 0;
    int bv = (t < NBLK) ? bsum[t] : 0;
    sh[t] = v; bs[t] = bv;
    __syncthreads();
    for (int d = 1; d < 256; d <<= 1) {
        int u1 = (t >= d) ? sh[t - d] : 0;
        int u2 = (t >= d) ? bs[t - d] : 0;
        __syncthreads();
        sh[t] += u1; bs[t] += u2;
        __syncthreads();
    }
    if (t == (int)blockIdx.x) basev = bs[t] - bv;  // exclusive prefix for this block
    __syncthreads();
    int excl = sh[t] - v + basev;
    if (i < NN) { off[i] = excl; cur[i] = excl; }
    if (i == NN - 1) off[NN] = NE;
}

// -------------------- CSR build: bucket fill (int4 reads) ---------------------
__global__ __launch_bounds__(256) void fill_kernel(
    const int* __restrict__ rows, int* __restrict__ cur, int* __restrict__ eid)
{
    int base = (blockIdx.x * 256 + threadIdx.x) * 4;
    if (base < NE) {
        int4 r = *reinterpret_cast<const int4*>(rows + base);
        eid[atomicAdd(&cur[r.x], 1)] = base + 0;
        eid[atomicAdd(&cur[r.y], 1)] = base + 1;
        eid[atomicAdd(&cur[r.z], 1)] = base + 2;
        eid[atomicAdd(&cur[r.w], 1)] = base + 3;
    }
}

// -------------------- gather: msgbf[n] = bf16(sum of ef rows) ------------------
// one wave per node; 16 lanes x 32B per edge row -> 4 edges in flight
__global__ __launch_bounds__(256) void gather_kernel(
    const float* __restrict__ ef, const int* __restrict__ off,
    const int* __restrict__ eid, uint4* __restrict__ msgbf)
{
    int node = blockIdx.x * 4 + (threadIdx.x >> 6);
    if (node >= NN) return;
    int lane = threadIdx.x & 63;
    int eg = lane >> 4;        // edge slot 0..3
    int lc = lane & 15;        // 32B column segment
    int b = off[node], e = off[node + 1];
    float acc[8];
    #pragma unroll
    for (int j = 0; j < 8; ++j) acc[j] = 0.f;
    for (int i = b + eg; i < e; i += 4) {
        int ed = eid[i];
        const float* src = ef + (size_t)ed * HD + lc * 8;
        float4 v0 = *reinterpret_cast<const float4*>(src);
        float4 v1 = *reinterpret_cast<const float4*>(src + 4);
        acc[0] += v0.x; acc[1] += v0.y; acc[2] += v0.z; acc[3] += v0.w;
        acc[4] += v1.x; acc[5] += v1.y; acc[6] += v1.z; acc[7] += v1.w;
    }
    #pragma unroll
    for (int j = 0; j < 8; ++j) {
        acc[j] += __shfl_xor(acc[j], 16);
        acc[j] += __shfl_xor(acc[j], 32);
    }
    if (eg == 0) {
        uint4 pk;
        pk.x = (unsigned)f2b(acc[0]) | ((unsigned)f2b(acc[1]) << 16);
        pk.y = (unsigned)f2b(acc[2]) | ((unsigned)f2b(acc[3]) << 16);
        pk.z = (unsigned)f2b(acc[4]) | ((unsigned)f2b(acc[5]) << 16);
        pk.w = (unsigned)f2b(acc[6]) | ((unsigned)f2b(acc[7]) << 16);
        msgbf[(size_t)node * 16 + lc] = pk;
    }
}

// ---- fused12 tail: assumes As (A-tile bf16) + Ws (W1t) staged & synced,
//      b1s/b2s/lws/lbs loaded. Computes h, s, writes hbf/sout, atomics stats. --
__device__ __forceinline__ void fused12_tail(
    char* smem, const short* __restrict__ w2t,
    unsigned short* __restrict__ hbf, float* __restrict__ sout,
    float* __restrict__ sums_base, int m0)
{
    short* As = (short*)(smem);
    short* Ws = (short*)(smem + 17408);
    short* Ts = (short*)(smem + 52224);
    float* b1s = (float*)(smem + 69632);
    float* b2s = (float*)(smem + 70144);
    float* lws = (float*)(smem + 70656);
    float* lbs = (float*)(smem + 76288);
    float* hF = (float*)(smem);            // stats overlay
    float* sS = (float*)(smem + 33792);    // stats overlay

    const int tid = threadIdx.x;
    const int lane = tid & 63;
    const int wv = tid >> 6;
    const int fr = lane & 15;
    const int fc = lane >> 4;

    f4v acc[8];
    #pragma unroll
    for (int ct = 0; ct < 8; ++ct) acc[ct] = (f4v){0.f, 0.f, 0.f, 0.f};
    {
        const short* ap = As + (wv * 16 + fr) * 136 + fc * 8;
        const short* bp = Ws + fr * 136 + fc * 8;
        #pragma unroll
        for (int ks = 0; ks < 4; ++ks) {
            s8v a = *(const s8v*)(ap + ks * 32);
            #pragma unroll
            for (int ct = 0; ct < 8; ++ct) {
                s8v b = *(const s8v*)(bp + ct * 16 * 136 + ks * 32);
                acc[ct] = __builtin_amdgcn_mfma_f32_16x16x32_bf16(a, b, acc[ct], 0, 0, 0);
            }
        }
    }
    // t = softplus(.+b1) -> Ts bf16
    {
        int rb = wv * 16 + fc * 4;
        #pragma unroll
        for (int ct = 0; ct < 8; ++ct) {
            int col = ct * 16 + fr;
            float bv = b1s[col];
            #pragma unroll
            for (int r = 0; r < 4; ++r)
                Ts[(rb + r) * 136 + col] = (short)f2b(softplus_f(acc[ct][r] + bv));
        }
    }
    __syncthreads();
    // stage W2t over Ws
    {
        int col = tid >> 1, seg = (tid & 1) * 64;
        const short* src = w2t + (size_t)col * 128 + seg;
        #pragma unroll
        for (int j = 0; j < 8; ++j)
            *(s8v*)&Ws[col * 136 + seg + 8 * j] = *(const s8v*)(src + 8 * j);
    }
    __syncthreads();

    #pragma unroll
    for (int ct = 0; ct < 8; ++ct) acc[ct] = (f4v){0.f, 0.f, 0.f, 0.f};
    {
        const short* ap = Ts + (wv * 16 + fr) * 136 + fc * 8;
        const short* bp = Ws + fr * 136 + fc * 8;
        #pragma unroll
        for (int ks = 0; ks < 4; ++ks) {
            s8v a = *(const s8v*)(ap + ks * 32);
            #pragma unroll
            for (int ct = 0; ct < 8; ++ct) {
                s8v b = *(const s8v*)(bp + ct * 16 * 136 + ks * 32);
                acc[ct] = __builtin_amdgcn_mfma_f32_16x16x32_bf16(a, b, acc[ct], 0, 0, 0);
            }
        }
    }
    // h = acc + b2
    #pragma unroll
    for (int ct = 0; ct < 8; ++ct) {
        float bv = b2s[ct * 16 + fr];
        #pragma unroll
        for (int r = 0; r < 4; ++r) acc[ct][r] += bv;
    }
    // s = softmax(h @ linW + linb) via 16-lane butterfly
    float dot[4][10];
    #pragma unroll
    for (int r = 0; r < 4; ++r)
        #pragma unroll
        for (int g = 0; g < 10; ++g) dot[r][g] = 0.f;
    #pragma unroll
    for (int ct = 0; ct < 8; ++ct) {
        #pragma unroll
        for (int g = 0; g < 10; ++g) {
            float lwv = lws[(ct * 16 + fr) * 11 + g];
            #pragma unroll
            for (int r = 0; r < 4; ++r) dot[r][g] += acc[ct][r] * lwv;
        }
    }
    #pragma unroll
    for (int r = 0; r < 4; ++r)
        #pragma unroll
        for (int g = 0; g < 10; ++g) {
            float v = dot[r][g];
            v += __shfl_xor(v, 1);
            v += __shfl_xor(v, 2);
            v += __shfl_xor(v, 4);
            v += __shfl_xor(v, 8);
            dot[r][g] = v + lbs[g];
        }
    #pragma unroll
    for (int r = 0; r < 4; ++r) {
        float m = dot[r][0];
        #pragma unroll
        for (int g = 1; g < 10; ++g) m = fmaxf(m, dot[r][g]);
        float sum = 0.f;
        #pragma unroll
        for (int g = 0; g < 10; ++g) { dot[r][g] = expf(dot[r][g] - m); sum += dot[r][g]; }
        float inv = 1.f / sum;
        #pragma unroll
        for (int g = 0; g < 10; ++g) dot[r][g] *= inv;
    }
    const int growb = m0 + wv * 16 + fc * 4;
    const int rlocb = wv * 16 + fc * 4;
    unsigned short hq[8][4];
    #pragma unroll
    for (int ct = 0; ct < 8; ++ct) {
        int col = ct * 16 + fr;
        #pragma unroll
        for (int r = 0; r < 4; ++r) {
            hq[ct][r] = f2b(acc[ct][r]);
            int row = growb + r;
            if (row < NN) hbf[(size_t)row * 128 + col] = hq[ct][r];
        }
    }
    if (fr < 10) {
        #pragma unroll
        for (int r = 0; r < 4; ++r) {
            int row = growb + r;
            if (row < NN) {
                float v = 0.f;
                #pragma unroll
                for (int g = 0; g < 10; ++g) v = (fr == g) ? dot[r][g] : v;
                sout[(size_t)row * 10 + fr] = v;
            }
        }
    }
    // block-local stats -> atomics into one of NCOPY spread copies
    __syncthreads();   // all waves done with As/Ws/Ts
    #pragma unroll
    for (int ct = 0; ct < 8; ++ct) {
        int col = ct * 16 + fr;
        #pragma unroll
        for (int r = 0; r < 4; ++r) {
            bool valid = (growb + r) < NN;
            hF[(rlocb + r) * 132 + col] = valid ? b2f(hq[ct][r]) : 0.f;
        }
    }
    if (fr < 10) {
        #pragma unroll
        for (int r = 0; r < 4; ++r) {
            bool valid = (growb + r) < NN;
            float v = 0.f;
            #pragma unroll
            for (int g = 0; g < 10; ++g) v = (fr == g) ? dot[r][g] : v;
            sS[(rlocb + r) * 10 + fr] = valid ? v : 0.f;
        }
    }
    __syncthreads();
    {
        float* sums = sums_base + (size_t)(blockIdx.x & (NCOPY - 1)) * 2560;
        const int c = tid & 127;
        const int g0 = (tid >> 7) * 5;
        float a1[5], a2[5];
        #pragma unroll
        for (int q = 0; q < 5; ++q) { a1[q] = 0.f; a2[q] = 0.f; }
        for (int n = 0; n < 64; ++n) {
            float hv = hF[n * 132 + c];
            #pragma unroll
            for (int q = 0; q < 5; ++q) {
                float pv = sS[n * 10 + g0 + q] * hv;
                a1[q] += pv;
                a2[q] += pv * pv;
            }
        }
        #pragma unroll
        for (int q = 0; q < 5; ++q) {
            atomicAdd(&sums[(g0 + q) * 128 + c], a1[q]);
            atomicAdd(&sums[1280 + (g0 + q) * 128 + c], a2[q]);
        }
    }
}

// ---- kernel: combine (K=320 MFMA, bf16 inputs) + fused12 block a -------------
__global__ __launch_bounds__(256) void combine_f12a_kernel(
    const unsigned short* __restrict__ xbf, const short* __restrict__ msgbf,
    const float* __restrict__ gf, const short* __restrict__ wct,
    const float* __restrict__ bc,
    const short* __restrict__ w1t, const short* __restrict__ w2t,
    const float* __restrict__ b1, const float* __restrict__ b2,
    const float* __restrict__ linW, const float* __restrict__ linb,
    unsigned short* __restrict__ out0bf, unsigned short* __restrict__ hbf,
    float* __restrict__ sout, float* __restrict__ sums)
{
    __shared__ __align__(16) char smem[SMEM_BYTES];
    short* cAs = (short*)(smem);            // combine A: 64x72 bf16
    short* cWs = (short*)(smem + 9216);     // combine W: 128x72 bf16
    short* As  = (short*)(smem);
    short* Ws  = (short*)(smem + 17408);
    float* b1s = (float*)(smem + 69632);
    float* b2s = (float*)(smem + 70144);
    float* lws = (float*)(smem + 70656);
    float* lbs = (float*)(smem + 76288);
    float* bcs = (float*)(smem + 76352);

    const int tid = threadIdx.x;
    const int m0 = blockIdx.x * 64;
    if (tid < 128) { bcs[tid] = bc[tid]; b1s[tid] = b1[tid]; b2s[tid] = b2[tid]; }
    for (int i = tid; i < 1280; i += 256) lws[(i / 10) * 11 + (i % 10)] = linW[i];
    if (tid < 10) lbs[tid] = linb[tid];
    const int lane = tid & 63;
    const int wv = tid >> 6;
    const int fr = lane & 15;
    const int fc = lane >> 4;

    f4v acc[8];
    #pragma unroll
    for (int ct = 0; ct < 8; ++ct) acc[ct] = (f4v){0.f, 0.f, 0.f, 0.f};

    const int arow = tid >> 2;
    const int aseg = (tid & 3) * 16;
    const int wcol = tid >> 1;
    const int wseg = (tid & 1) * 32;

    for (int c = 0; c < 5; ++c) {
        const int k0 = c * 64;
        {
            short tmp[16];
            int grow = m0 + arow;
            if (grow >= NN) {
                #pragma unroll
                for (int j = 0; j < 16; ++j) tmp[j] = 0;
            } else if (c < 2) {
                const short* src = (const short*)xbf + (size_t)grow * 128 + k0 + aseg;
                *(s8v*)tmp = *(const s8v*)src;
                *(s8v*)(tmp + 8) = *(const s8v*)(src + 8);
            } else if (c < 4) {
                const short* src = msgbf + (size_t)grow * 128 + (k0 - 128) + aseg;
                *(s8v*)tmp = *(const s8v*)src;
                *(s8v*)(tmp + 8) = *(const s8v*)(src + 8);
            } else {
                const float* src = gf + aseg;
                #pragma unroll
                for (int q = 0; q < 4; ++q) {
                    float4 v = *reinterpret_cast<const float4*>(src + 4 * q);
                    tmp[4*q+0] = (short)f2b(v.x); tmp[4*q+1] = (short)f2b(v.y);
                    tmp[4*q+2] = (short)f2b(v.z); tmp[4*q+3] = (short)f2b(v.w);
                }
            }
            *(s8v*)&cAs[arow * 72 + aseg] = *(s8v*)tmp;
            *(s8v*)&cAs[arow * 72 + aseg + 8] = *(s8v*)(tmp + 8);
        }
        {
            const short* src = wct + (size_t)wcol * 320 + k0 + wseg;
            #pragma unroll
            for (int j = 0; j < 4; ++j)
                *(s8v*)&cWs[wcol * 72 + wseg + 8 * j] = *(const s8v*)(src + 8 * j);
        }
        __syncthreads();
        const short* ap = cAs + (wv * 16 + fr) * 72 + fc * 8;
        const short* bp = cWs + fr * 72 + fc * 8;
        #pragma unroll
        for (int ks = 0; ks < 2; ++ks) {
            s8v a = *(const s8v*)(ap + ks * 32);
            #pragma unroll
            for (int ct = 0; ct < 8; ++ct) {
                s8v b = *(const s8v*)(bp + ct * 16 * 72 + ks * 32);
                acc[ct] = __builtin_amdgcn_mfma_f32_16x16x32_bf16(a, b, acc[ct], 0, 0, 0);
            }
        }
        __syncthreads();   // staging buffers free after this
    }
    // epilogue: out0 = softplus(acc + bc); write global + LDS A-tile for fused12
    const int rbase = m0 + wv * 16 + fc * 4;
    const int rloc  = wv * 16 + fc * 4;
    #pragma unroll
    for (int ct = 0; ct < 8; ++ct) {
        int col = ct * 16 + fr;
        float bv = bcs[col];
        #pragma unroll
        for (int r = 0; r < 4; ++r) {
            unsigned short q = f2b(softplus_f(acc[ct][r] + bv));
            bool valid = (rbase + r) < NN;
            if (valid) out0bf[(size_t)(rbase + r) * 128 + col] = q;
            As[(rloc + r) * 136 + col] = valid ? (short)q : (short)0;
        }
    }
    // stage W1t
    {
        int col = tid >> 1, seg = (tid & 1) * 64;
        const short* src = w1t + (size_t)col * 128 + seg;
        #pragma unroll
        for (int j = 0; j < 8; ++j)
            *(s8v*)&Ws[col * 136 + seg + 8 * j] = *(const s8v*)(src + 8 * j);
    }
    __syncthreads();
    fused12_tail(smem, w2t, hbf, sout, sums, m0);
}

// ---- kernel: apply block a (inline finalize, 8-copy merge) + fused12 block b -
__global__ __launch_bounds__(256) void apply_f12b_kernel(
    const unsigned short* __restrict__ out0bf,
    const float* __restrict__ sums_a,
    const float* __restrict__ gamma_a, const float* __restrict__ beta_a,
    const short* __restrict__ w1t, const short* __restrict__ w2t,
    const float* __restrict__ b1, const float* __restrict__ b2,
    const float* __restrict__ linW, const float* __restrict__ linb,
    unsigned short* __restrict__ out1bf,
    unsigned short* __restrict__ hbf,     // in: h_a rows (own tile); out: h_b
    float* __restrict__ sout,             // in: s_a rows (own tile); out: s_b
    float* __restrict__ sums_b)
{
    __shared__ __align__(16) char smem[SMEM_BYTES];
    float* ws_  = (float*)(smem);            // 1280
    float* mus_ = (float*)(smem + 5120);     // 1280
    float* ks_  = (float*)(smem + 10240);    // 128
    float* ss_  = (float*)(smem + 10752);    // 640
    short* As   = (short*)(smem);
    short* Ws   = (short*)(smem + 17408);
    float* b1s  = (float*)(smem + 69632);
    float* b2s  = (float*)(smem + 70144);
    float* lws  = (float*)(smem + 70656);
    float* lbs  = (float*)(smem + 76288);

    const int tid = threadIdx.x;
    const int m0 = blockIdx.x * 64;
    if (tid < 128) { b1s[tid] = b1[tid]; b2s[tid] = b2[tid]; }
    for (int i = tid; i < 1280; i += 256) lws[(i / 10) * 11 + (i % 10)] = linW[i];
    if (tid < 10) lbs[tid] = linb[tid];
    const float invn = 1.f / (float)NN;
    for (int idx = tid; idx < 1280; idx += 256) {
        float s1 = 0.f, s2 = 0.f;
        #pragma unroll
        for (int k = 0; k < NCOPY; ++k) {
            s1 += sums_a[(size_t)k * 2560 + idx];
            s2 += sums_a[(size_t)k * 2560 + idx + 1280];
        }
        float mu = s1 * invn;
        float var = s2 * invn - mu * mu;
        float wg = rsqrtf(var + EPSV) * gamma_a[idx];
        ws_[idx] = wg;
        mus_[idx] = mu;
    }
    for (int i = tid; i < 640; i += 256) {
        int n = m0 + i / 10;
        ss_[i] = (n < NN) ? sout[(size_t)n * 10 + i % 10] : 0.f;
    }
    // stage W1t (disjoint LDS region; overlaps nothing in phase A)
    {
        int col = tid >> 1, seg = (tid & 1) * 64;
        const short* src = w1t + (size_t)col * 128 + seg;
        #pragma unroll
        for (int j = 0; j < 8; ++j)
            *(s8v*)&Ws[col * 136 + seg + 8 * j] = *(const s8v*)(src + 8 * j);
    }
    __syncthreads();
    if (tid < 128) {
        float kacc = 0.f;
        #pragma unroll
        for (int g = 0; g < NG; ++g) {
            int idx = g * 128 + tid;
            kacc += beta_a[idx] - mus_[idx] * ws_[idx];
        }
        ks_[tid] = kacc;
    }
    __syncthreads();
    // apply math: out1 = out0 + h + LAM*(h*A + K); keep bf16 vals for A-tile
    const int tc = tid & 31, rg = tid >> 5;
    ushort4 vals[8];
    #pragma unroll
    for (int p = 0; p < 8; ++p) {
        int nl = p * 8 + rg;
        int n = m0 + nl;
        if (n >= NN) { vals[p].x = vals[p].y = vals[p].z = vals[p].w = 0; continue; }
        float A0 = 0.f, A1 = 0.f, A2 = 0.f, A3 = 0.f;
        #pragma unroll
        for (int g = 0; g < 10; ++g) {
            float sv = ss_[nl * 10 + g];
            float4 wv4 = *reinterpret_cast<const float4*>(&ws_[g * 128 + tc * 4]);
            A0 += sv * wv4.x; A1 += sv * wv4.y; A2 += sv * wv4.z; A3 += sv * wv4.w;
        }
        ushort4 hv4 = *reinterpret_cast<const ushort4*>(hbf + (size_t)n * 128 + tc * 4);
        ushort4 ov4 = *reinterpret_cast<const ushort4*>(out0bf + (size_t)n * 128 + tc * 4);
        float h0 = b2f(hv4.x), h1 = b2f(hv4.y), h2 = b2f(hv4.z), h3 = b2f(hv4.w);
        float r0 = b2f(ov4.x) + h0 + LAM * (h0 * A0 + ks_[tc * 4 + 0]);
        float r1 = b2f(ov4.y) + h1 + LAM * (h1 * A1 + ks_[tc * 4 + 1]);
        float r2 = b2f(ov4.z) + h2 + LAM * (h2 * A2 + ks_[tc * 4 + 2]);
        float r3 = b2f(ov4.w) + h3 + LAM * (h3 * A3 + ks_[tc * 4 + 3]);
        ushort4 o;
        o.x = f2b(r0); o.y = f2b(r1); o.z = f2b(r2); o.w = f2b(r3);
        *reinterpret_cast<ushort4*>(out1bf + (size_t)n * 128 + tc * 4) = o;
        vals[p] = o;
    }
    __syncthreads();   // phase-A LDS reads complete
    // write A-tile for fused12_b
    #pragma unroll
    for (int p = 0; p < 8; ++p) {
        int row = p * 8 + rg;
        *reinterpret_cast<ushort4*>(&As[row * 136 + tc * 4]) = vals[p];
    }
    __syncthreads();
    fused12_tail(smem, w2t, hbf, sout, sums_b, m0);
}

// -------------------- apply last: out = out1 + h_b + DGN + initial ------------
__global__ __launch_bounds__(256) void apply_last_kernel(
    const unsigned short* __restrict__ out1bf,
    const unsigned short* __restrict__ hbf,
    const float* __restrict__ s, const float* __restrict__ sums,
    const float* __restrict__ gamma, const float* __restrict__ beta,
    const unsigned short* __restrict__ out0bf,
    float* __restrict__ dstf)
{
    __shared__ __align__(16) float ws_[1280];
    __shared__ float mus_[1280];
    __shared__ float ks_[128];
    __shared__ float ss_[640];
    const int tid = threadIdx.x;
    const int m0 = blockIdx.x * 64;
    const float invn = 1.f / (float)NN;
    for (int idx = tid; idx < 1280; idx += 256) {
        float s1 = 0.f, s2 = 0.f;
        #pragma unroll
        for (int k = 0; k < NCOPY; ++k) {
            s1 += sums[(size_t)k * 2560 + idx];
            s2 += sums[(size_t)k * 2560 + idx + 1280];
        }
        float mu = s1 * invn;
        float var = s2 * invn - mu * mu;
        float wg = rsqrtf(var + EPSV) * gamma[idx];
        ws_[idx] = wg;
        mus_[idx] = mu;
    }
    for (int i = tid; i < 640; i += 256) {
        int n = m0 + i / 10;
        ss_[i] = (n < NN) ? s[(size_t)n * 10 + i % 10] : 0.f;
    }
    __syncthreads();
    if (tid < 128) {
        float kacc = 0.f;
        #pragma unroll
        for (int g = 0; g < NG; ++g) {
            int idx = g * 128 + tid;
            kacc += beta[idx] - mus_[idx] * ws_[idx];
        }
        ks_[tid] = kacc;
    }
    __syncthreads();
    const int tc = tid & 31, rg = tid >> 5;
    #pragma unroll
    for (int p = 0; p < 8; ++p) {
        int nl = p * 8 + rg;
        int n = m0 + nl;
        if (n >= NN) continue;
        float A0 = 0.f, A1 = 0.f, A2 = 0.f, A3 = 0.f;
        #pragma unroll
        for (int g = 0; g < 10; ++g) {
            float sv = ss_[nl * 10 + g];
            float4 wv4 = *reinterpret_cast<const float4*>(&ws_[g * 128 + tc * 4]);
            A0 += sv * wv4.x; A1 += sv * wv4.y; A2 += sv * wv4.z; A3 += sv * wv4.w;
        }
        ushort4 hv4 = *reinterpret_cast<const ushort4*>(hbf + (size_t)n * 128 + tc * 4);
        ushort4 ov4 = *reinterpret_cast<const ushort4*>(out1bf + (size_t)n * 128 + tc * 4);
        ushort4 iv4 = *reinterpret_cast<const ushort4*>(out0bf + (size_t)n * 128 + tc * 4);
        float h0 = b2f(hv4.x), h1 = b2f(hv4.y), h2 = b2f(hv4.z), h3 = b2f(hv4.w);
        float r0 = b2f(ov4.x) + h0 + LAM * (h0 * A0 + ks_[tc * 4 + 0]) + b2f(iv4.x);
        float r1 = b2f(ov4.y) + h1 + LAM * (h1 * A1 + ks_[tc * 4 + 1]) + b2f(iv4.y);
        float r2 = b2f(ov4.z) + h2 + LAM * (h2 * A2 + ks_[tc * 4 + 2]) + b2f(iv4.z);
        float r3 = b2f(ov4.w) + h3 + LAM * (h3 * A3 + ks_[tc * 4 + 3]) + b2f(iv4.w);
        *reinterpret_cast<float4*>(dstf + (size_t)n * 128 + tc * 4) =
            make_float4(r0, r1, r2, r3);
    }
}

// ------------------------------------------------------------------------------
extern "C" void kernel_launch(void* const* d_in, const int* in_sizes, int n_in,
                              void* d_out, int out_size, void* d_ws, size_t ws_size,
                              hipStream_t stream)
{
    const float* x    = (const float*)d_in[0];
    const int*   eidx = (const int*)  d_in[1];
    const float* ef   = (const float*)d_in[2];
    const float* gf   = (const float*)d_in[3];
    const float* Wc   = (const float*)d_in[4];
    const float* bc   = (const float*)d_in[5];

    float* p = (float*)d_ws;
    // zeroed region (single memset): [cnt NN ints][sums_a NCOPY*2560][sums_b ..]
    int*   cnt    = (int*)p;                      p += NN;
    float* sums_a = p;                            p += (size_t)NCOPY * 2560;
    float* sums_b = p;                            p += (size_t)NCOPY * 2560;
    unsigned short* msgbf  = (unsigned short*)p;  p += (size_t)NN * 64;
    unsigned short* out0bf = (unsigned short*)p;  p += (size_t)NN * 64;
    unsigned short* out1bf = (unsigned short*)p;  p += (size_t)NN * 64;
    unsigned short* hbf    = (unsigned short*)p;  p += (size_t)NN * 64;
    unsigned short* xbf    = (unsigned short*)p;  p += (size_t)NN * 64;
    float* sbuf = p;                              p += (size_t)NN * 10;
    short* wct  = (short*)p;                      // 40960 shorts
    short* wts  = wct + 40960;                    // 4*16384 shorts

    // CSR scratch aliased into buffers written later:
    int* off   = (int*)out1bf;           // NN+1  (out1bf written in apply_f12b)
    int* cur   = off + NN + 1;           // NN
    int* bsum  = cur + NN;               // NBLK
    int* eid   = (int*)hbf;              // NE    (hbf written in combine_f12a)

    // zero cnt + both stat-sum regions in one memset
    hipMemsetAsync(cnt, 0, sizeof(int) * (NN + 2 * NCOPY * 2560), stream);

    // histogram + weight prep + x->bf16 (merged, disjoint block ranges)
    hist_prep_kernel<<<EBLOCKS + PBLOCKS + XBLOCKS, 256, 0, stream>>>(
        eidx, cnt, Wc, (const float*)d_in[6], (const float*)d_in[8],
        (const float*)d_in[14], (const float*)d_in[16], wct, wts, x, xbf);

    scan1_kernel<<<NBLK, 256, 0, stream>>>(cnt, bsum);
    scan3_kernel<<<NBLK, 256, 0, stream>>>(cnt, bsum, off, cur);
    fill_kernel <<<EBLOCKS, 256, 0, stream>>>(eidx, cur, eid);
    gather_kernel<<<(NN + 3) / 4, 256, 0, stream>>>(ef, off, eid, (uint4*)msgbf);

    const short* w1ta = wts;
    const short* w2ta = wts + 16384;
    const short* w1tb = wts + 32768;
    const short* w2tb = wts + 49152;

    // combine + block a (writes out0bf, h_a, s_a; atomics sums_a copies)
    combine_f12a_kernel<<<GBLK, 256, 0, stream>>>(
        xbf, (const short*)msgbf, gf, wct, bc,
        w1ta, w2ta, (const float*)d_in[7], (const float*)d_in[9],
        (const float*)d_in[10], (const float*)d_in[11],
        out0bf, hbf, sbuf, sums_a);

    // apply_a + block b (merges sums_a copies; writes out1bf, h_b, s_b)
    apply_f12b_kernel<<<GBLK, 256, 0, stream>>>(
        out0bf, sums_a, (const float*)d_in[12], (const float*)d_in[13],
        w1tb, w2tb, (const float*)d_in[15], (const float*)d_in[17],
        (const float*)d_in[18], (const float*)d_in[19],
        out1bf, hbf, sbuf, sums_b);

    // final apply: d_out = out1 + h_b + DGN_b + initial(out0)
    apply_last_kernel<<<GBLK, 256, 0, stream>>>(
        out1bf, hbf, sbuf, sums_b, (const float*)d_in[20], (const float*)d_in[21],
        out0bf, (float*)d_out);
}

// Round 12
// 385.445 us; speedup vs baseline: 2.3766x; 1.0321x over previous
//
#include <hip/hip_runtime.h>
#include <math.h>

// Problem constants
constexpr int NN = 50000;      // nodes
constexpr int NE = 800000;     // edges
constexpr int HD = 128;        // hidden
constexpr int NG = 10;         // groups
constexpr float LAM = 0.01f;
constexpr float EPSV = 1e-5f;
constexpr int NBLK = (NN + 255) / 256;     // 196 scan blocks
constexpr int GBLK = (NN + 63) / 64;       // 782 row-tile blocks
constexpr int NCOPY = 8;                   // stats atomic spread copies

typedef __attribute__((ext_vector_type(8))) short s8v;   // 8 bf16 (4 VGPRs)
typedef __attribute__((ext_vector_type(4))) float f4v;   // MFMA acc

constexpr int SMEM_BYTES = 76864;

__device__ __forceinline__ float softplus_f(float x) {
    return fmaxf(x, 0.f) + log1pf(expf(-fabsf(x)));
}
__device__ __forceinline__ unsigned short f2b(float f) {
    unsigned u = __float_as_uint(f);
    unsigned r = (u + 0x7FFFu + ((u >> 16) & 1u)) >> 16;
    return (unsigned short)r;
}
__device__ __forceinline__ float b2f(unsigned short u) {
    return __uint_as_float(((unsigned)u) << 16);
}

// ------ hist (int4 reads) + weight prep + x->bf16, disjoint block ranges ------
constexpr int EBLOCKS = (NE / 4 + 255) / 256;            // 782
constexpr int PBLOCKS = 416;                             // weight prep
constexpr int XBLOCKS = (NN * 32 + 255) / 256;           // 6250 (x convert, f4)
__global__ __launch_bounds__(256) void hist_prep_kernel(
    const int* __restrict__ rows, int* __restrict__ cnt,
    const float* __restrict__ Wc,
    const float* __restrict__ W1a, const float* __restrict__ W2a,
    const float* __restrict__ W1b, const float* __restrict__ W2b,
    short* __restrict__ wct, short* __restrict__ wts,
    const float* __restrict__ x, unsigned short* __restrict__ xbf)
{
    int bid = blockIdx.x;
    if (bid < EBLOCKS) {
        int base = (bid * 256 + threadIdx.x) * 4;
        if (base < NE) {   // NE % 4 == 0
            int4 r = *reinterpret_cast<const int4*>(rows + base);
            atomicAdd(&cnt[r.x], 1);
            atomicAdd(&cnt[r.y], 1);
            atomicAdd(&cnt[r.z], 1);
            atomicAdd(&cnt[r.w], 1);
        }
    } else if (bid < EBLOCKS + PBLOCKS) {
        int i = (bid - EBLOCKS) * 256 + threadIdx.x;
        if (i < 40960) {
            int n = i / 320, kk = i % 320;
            wct[i] = (short)f2b(Wc[kk * 128 + n]);
        } else if (i < 40960 + 4 * 16384) {
            int j = i - 40960;
            int mat = j >> 14;
            int idx = j & 16383;
            int n = idx >> 7, kk = idx & 127;
            const float* src = (mat == 0) ? W1a : (mat == 1) ? W2a
                             : (mat == 2) ? W1b : W2b;
            wts[j] = (short)f2b(src[kk * 128 + n]);
        }
    } else {
        int i = (bid - EBLOCKS - PBLOCKS) * 256 + threadIdx.x;
        if (i < NN * 32) {
            float4 v = reinterpret_cast<const float4*>(x)[i];
            ushort4 o;
            o.x = f2b(v.x); o.y = f2b(v.y); o.z = f2b(v.z); o.w = f2b(v.w);
            reinterpret_cast<ushort4*>(xbf)[i] = o;
        }
    }
}

// -------------------- scan stage 1: per-block sums ----------------------------
__global__ __launch_bounds__(256) void scan1_kernel(
    const int* __restrict__ cnt, int* __restrict__ bsum)
{
    __shared__ int red[256];
    int t = threadIdx.x;
    int i = blockIdx.x * 256 + t;
    red[t] = (i < NN) ? cnt[i] : 0;
    __syncthreads();
    for (int d = 128; d > 0; d >>= 1) {
        if (t < d) red[t] += red[t + d];
        __syncthreads();
    }
    if (t == 0) bsum[blockIdx.x] = red[0];
}

// ------ scan stage 2+3 merged: every block scans the 196 partials in LDS ------
__global__ __launch_bounds__(256) void scan3_kernel(
    const int* __restrict__ cnt, const int* __restrict__ bsum,
    int* __restrict__ off, int* __restrict__ cur)
{
    __shared__ int sh[256];
    __shared__ int bs[256];
    __shared__ int basev;
    int t = threadIdx.x;
    int i = blockIdx.x * 256 + t;
    int v  = (i < NN) ? cnt[i] : 0;
    int bv = (t < NBLK) ? bsum[t] : 0;
    sh[t] = v; bs[t] = bv;
    __syncthreads();
    for (int d = 1; d < 256; d <<= 1) {
        int u1 = (t >= d) ? sh[t - d] : 0;
        int u2 = (t >= d) ? bs[t - d] : 0;
        __syncthreads();
        sh[t] += u1; bs[t] += u2;
        __syncthreads();
    }
    if (t == (int)blockIdx.x) basev = bs[t] - bv;  // exclusive prefix for this block
    __syncthreads();
    int excl = sh[t] - v + basev;
    if (i < NN) { off[i] = excl; cur[i] = excl; }
    if (i == NN - 1) off[NN] = NE;
}

// -------------------- CSR build: bucket fill (int4 reads) ---------------------
__global__ __launch_bounds__(256) void fill_kernel(
    const int* __restrict__ rows, int* __restrict__ cur, int* __restrict__ eid)
{
    int base = (blockIdx.x * 256 + threadIdx.x) * 4;
    if (base < NE) {
        int4 r = *reinterpret_cast<const int4*>(rows + base);
        eid[atomicAdd(&cur[r.x], 1)] = base + 0;
        eid[atomicAdd(&cur[r.y], 1)] = base + 1;
        eid[atomicAdd(&cur[r.z], 1)] = base + 2;
        eid[atomicAdd(&cur[r.w], 1)] = base + 3;
    }
}

// -------------------- gather: msgbf[n] = bf16(sum of ef rows) ------------------
// one wave per node; 8 lanes x 64B per edge row -> 8 edges in flight,
// 32 outstanding 16B loads per wave (4x the previous MLP; fixes the
// latency-bound regime: need ~675 loads/CU in flight at 900cy HBM latency).
__global__ __launch_bounds__(256) void gather_kernel(
    const float* __restrict__ ef, const int* __restrict__ off,
    const int* __restrict__ eid, uint4* __restrict__ msgbf)
{
    int node = blockIdx.x * 4 + (threadIdx.x >> 6);
    if (node >= NN) return;
    int lane = threadIdx.x & 63;
    int eg = lane >> 3;        // edge slot 0..7
    int lc = lane & 7;         // 64B column segment (16 floats)
    int b = off[node], e = off[node + 1];
    float acc[16];
    #pragma unroll
    for (int j = 0; j < 16; ++j) acc[j] = 0.f;
    for (int i = b + eg; i < e; i += 8) {
        int ed = eid[i];
        const float* src = ef + (size_t)ed * HD + lc * 16;
        float4 v0 = *reinterpret_cast<const float4*>(src);
        float4 v1 = *reinterpret_cast<const float4*>(src + 4);
        float4 v2 = *reinterpret_cast<const float4*>(src + 8);
        float4 v3 = *reinterpret_cast<const float4*>(src + 12);
        acc[0]  += v0.x; acc[1]  += v0.y; acc[2]  += v0.z; acc[3]  += v0.w;
        acc[4]  += v1.x; acc[5]  += v1.y; acc[6]  += v1.z; acc[7]  += v1.w;
        acc[8]  += v2.x; acc[9]  += v2.y; acc[10] += v2.z; acc[11] += v2.w;
        acc[12] += v3.x; acc[13] += v3.y; acc[14] += v3.z; acc[15] += v3.w;
    }
    #pragma unroll
    for (int j = 0; j < 16; ++j) {
        acc[j] += __shfl_xor(acc[j], 8);
        acc[j] += __shfl_xor(acc[j], 16);
        acc[j] += __shfl_xor(acc[j], 32);
    }
    if (eg == 0) {
        // lane lc owns bf16 cols [16*lc .. 16*lc+15] = 32B = 2 uint4
        uint4 p0, p1;
        p0.x = (unsigned)f2b(acc[0])  | ((unsigned)f2b(acc[1])  << 16);
        p0.y = (unsigned)f2b(acc[2])  | ((unsigned)f2b(acc[3])  << 16);
        p0.z = (unsigned)f2b(acc[4])  | ((unsigned)f2b(acc[5])  << 16);
        p0.w = (unsigned)f2b(acc[6])  | ((unsigned)f2b(acc[7])  << 16);
        p1.x = (unsigned)f2b(acc[8])  | ((unsigned)f2b(acc[9])  << 16);
        p1.y = (unsigned)f2b(acc[10]) | ((unsigned)f2b(acc[11]) << 16);
        p1.z = (unsigned)f2b(acc[12]) | ((unsigned)f2b(acc[13]) << 16);
        p1.w = (unsigned)f2b(acc[14]) | ((unsigned)f2b(acc[15]) << 16);
        msgbf[(size_t)node * 16 + lc * 2 + 0] = p0;
        msgbf[(size_t)node * 16 + lc * 2 + 1] = p1;
    }
}

// ---- fused12 tail: assumes As (A-tile bf16) + Ws (W1t) staged & synced,
//      b1s/b2s/lws/lbs loaded. Computes h, s, writes hbf/sout, atomics stats. --
__device__ __forceinline__ void fused12_tail(
    char* smem, const short* __restrict__ w2t,
    unsigned short* __restrict__ hbf, float* __restrict__ sout,
    float* __restrict__ sums_base, int m0)
{
    short* As = (short*)(smem);
    short* Ws = (short*)(smem + 17408);
    short* Ts = (short*)(smem + 52224);
    float* b1s = (float*)(smem + 69632);
    float* b2s = (float*)(smem + 70144);
    float* lws = (float*)(smem + 70656);
    float* lbs = (float*)(smem + 76288);
    float* hF = (float*)(smem);            // stats overlay
    float* sS = (float*)(smem + 33792);    // stats overlay

    const int tid = threadIdx.x;
    const int lane = tid & 63;
    const int wv = tid >> 6;
    const int fr = lane & 15;
    const int fc = lane >> 4;

    f4v acc[8];
    #pragma unroll
    for (int ct = 0; ct < 8; ++ct) acc[ct] = (f4v){0.f, 0.f, 0.f, 0.f};
    {
        const short* ap = As + (wv * 16 + fr) * 136 + fc * 8;
        const short* bp = Ws + fr * 136 + fc * 8;
        #pragma unroll
        for (int ks = 0; ks < 4; ++ks) {
            s8v a = *(const s8v*)(ap + ks * 32);
            #pragma unroll
            for (int ct = 0; ct < 8; ++ct) {
                s8v b = *(const s8v*)(bp + ct * 16 * 136 + ks * 32);
                acc[ct] = __builtin_amdgcn_mfma_f32_16x16x32_bf16(a, b, acc[ct], 0, 0, 0);
            }
        }
    }
    // t = softplus(.+b1) -> Ts bf16
    {
        int rb = wv * 16 + fc * 4;
        #pragma unroll
        for (int ct = 0; ct < 8; ++ct) {
            int col = ct * 16 + fr;
            float bv = b1s[col];
            #pragma unroll
            for (int r = 0; r < 4; ++r)
                Ts[(rb + r) * 136 + col] = (short)f2b(softplus_f(acc[ct][r] + bv));
        }
    }
    __syncthreads();
    // stage W2t over Ws
    {
        int col = tid >> 1, seg = (tid & 1) * 64;
        const short* src = w2t + (size_t)col * 128 + seg;
        #pragma unroll
        for (int j = 0; j < 8; ++j)
            *(s8v*)&Ws[col * 136 + seg + 8 * j] = *(const s8v*)(src + 8 * j);
    }
    __syncthreads();

    #pragma unroll
    for (int ct = 0; ct < 8; ++ct) acc[ct] = (f4v){0.f, 0.f, 0.f, 0.f};
    {
        const short* ap = Ts + (wv * 16 + fr) * 136 + fc * 8;
        const short* bp = Ws + fr * 136 + fc * 8;
        #pragma unroll
        for (int ks = 0; ks < 4; ++ks) {
            s8v a = *(const s8v*)(ap + ks * 32);
            #pragma unroll
            for (int ct = 0; ct < 8; ++ct) {
                s8v b = *(const s8v*)(bp + ct * 16 * 136 + ks * 32);
                acc[ct] = __builtin_amdgcn_mfma_f32_16x16x32_bf16(a, b, acc[ct], 0, 0, 0);
            }
        }
    }
    // h = acc + b2
    #pragma unroll
    for (int ct = 0; ct < 8; ++ct) {
        float bv = b2s[ct * 16 + fr];
        #pragma unroll
        for (int r = 0; r < 4; ++r) acc[ct][r] += bv;
    }
    // s = softmax(h @ linW + linb) via 16-lane butterfly
    float dot[4][10];
    #pragma unroll
    for (int r = 0; r < 4; ++r)
        #pragma unroll
        for (int g = 0; g < 10; ++g) dot[r][g] = 0.f;
    #pragma unroll
    for (int ct = 0; ct < 8; ++ct) {
        #pragma unroll
        for (int g = 0; g < 10; ++g) {
            float lwv = lws[(ct * 16 + fr) * 11 + g];
            #pragma unroll
            for (int r = 0; r < 4; ++r) dot[r][g] += acc[ct][r] * lwv;
        }
    }
    #pragma unroll
    for (int r = 0; r < 4; ++r)
        #pragma unroll
        for (int g = 0; g < 10; ++g) {
            float v = dot[r][g];
            v += __shfl_xor(v, 1);
            v += __shfl_xor(v, 2);
            v += __shfl_xor(v, 4);
            v += __shfl_xor(v, 8);
            dot[r][g] = v + lbs[g];
        }
    #pragma unroll
    for (int r = 0; r < 4; ++r) {
        float m = dot[r][0];
        #pragma unroll
        for (int g = 1; g < 10; ++g) m = fmaxf(m, dot[r][g]);
        float sum = 0.f;
        #pragma unroll
        for (int g = 0; g < 10; ++g) { dot[r][g] = expf(dot[r][g] - m); sum += dot[r][g]; }
        float inv = 1.f / sum;
        #pragma unroll
        for (int g = 0; g < 10; ++g) dot[r][g] *= inv;
    }
    const int growb = m0 + wv * 16 + fc * 4;
    const int rlocb = wv * 16 + fc * 4;
    unsigned short hq[8][4];
    #pragma unroll
    for (int ct = 0; ct < 8; ++ct) {
        int col = ct * 16 + fr;
        #pragma unroll
        for (int r = 0; r < 4; ++r) {
            hq[ct][r] = f2b(acc[ct][r]);
            int row = growb + r;
            if (row < NN) hbf[(size_t)row * 128 + col] = hq[ct][r];
        }
    }
    if (fr < 10) {
        #pragma unroll
        for (int r = 0; r < 4; ++r) {
            int row = growb + r;
            if (row < NN) {
                float v = 0.f;
                #pragma unroll
                for (int g = 0; g < 10; ++g) v = (fr == g) ? dot[r][g] : v;
                sout[(size_t)row * 10 + fr] = v;
            }
        }
    }
    // block-local stats -> atomics into one of NCOPY spread copies
    __syncthreads();   // all waves done with As/Ws/Ts
    #pragma unroll
    for (int ct = 0; ct < 8; ++ct) {
        int col = ct * 16 + fr;
        #pragma unroll
        for (int r = 0; r < 4; ++r) {
            bool valid = (growb + r) < NN;
            hF[(rlocb + r) * 132 + col] = valid ? b2f(hq[ct][r]) : 0.f;
        }
    }
    if (fr < 10) {
        #pragma unroll
        for (int r = 0; r < 4; ++r) {
            bool valid = (growb + r) < NN;
            float v = 0.f;
            #pragma unroll
            for (int g = 0; g < 10; ++g) v = (fr == g) ? dot[r][g] : v;
            sS[(rlocb + r) * 10 + fr] = valid ? v : 0.f;
        }
    }
    __syncthreads();
    {
        float* sums = sums_base + (size_t)(blockIdx.x & (NCOPY - 1)) * 2560;
        const int c = tid & 127;
        const int g0 = (tid >> 7) * 5;
        float a1[5], a2[5];
        #pragma unroll
        for (int q = 0; q < 5; ++q) { a1[q] = 0.f; a2[q] = 0.f; }
        for (int n = 0; n < 64; ++n) {
            float hv = hF[n * 132 + c];
            #pragma unroll
            for (int q = 0; q < 5; ++q) {
                float pv = sS[n * 10 + g0 + q] * hv;
                a1[q] += pv;
                a2[q] += pv * pv;
            }
        }
        #pragma unroll
        for (int q = 0; q < 5; ++q) {
            atomicAdd(&sums[(g0 + q) * 128 + c], a1[q]);
            atomicAdd(&sums[1280 + (g0 + q) * 128 + c], a2[q]);
        }
    }
}

// ---- kernel: combine (K=320 MFMA, bf16 inputs) + fused12 block a -------------
__global__ __launch_bounds__(256) void combine_f12a_kernel(
    const unsigned short* __restrict__ xbf, const short* __restrict__ msgbf,
    const float* __restrict__ gf, const short* __restrict__ wct,
    const float* __restrict__ bc,
    const short* __restrict__ w1t, const short* __restrict__ w2t,
    const float* __restrict__ b1, const float* __restrict__ b2,
    const float* __restrict__ linW, const float* __restrict__ linb,
    unsigned short* __restrict__ out0bf, unsigned short* __restrict__ hbf,
    float* __restrict__ sout, float* __restrict__ sums)
{
    __shared__ __align__(16) char smem[SMEM_BYTES];
    short* cAs = (short*)(smem);            // combine A: 64x72 bf16
    short* cWs = (short*)(smem + 9216);     // combine W: 128x72 bf16
    short* As  = (short*)(smem);
    short* Ws  = (short*)(smem + 17408);
    float* b1s = (float*)(smem + 69632);
    float* b2s = (float*)(smem + 70144);
    float* lws = (float*)(smem + 70656);
    float* lbs = (float*)(smem + 76288);
    float* bcs = (float*)(smem + 76352);

    const int tid = threadIdx.x;
    const int m0 = blockIdx.x * 64;
    if (tid < 128) { bcs[tid] = bc[tid]; b1s[tid] = b1[tid]; b2s[tid] = b2[tid]; }
    for (int i = tid; i < 1280; i += 256) lws[(i / 10) * 11 + (i % 10)] = linW[i];
    if (tid < 10) lbs[tid] = linb[tid];
    const int lane = tid & 63;
    const int wv = tid >> 6;
    const int fr = lane & 15;
    const int fc = lane >> 4;

    f4v acc[8];
    #pragma unroll
    for (int ct = 0; ct < 8; ++ct) acc[ct] = (f4v){0.f, 0.f, 0.f, 0.f};

    const int arow = tid >> 2;
    const int aseg = (tid & 3) * 16;
    const int wcol = tid >> 1;
    const int wseg = (tid & 1) * 32;

    for (int c = 0; c < 5; ++c) {
        const int k0 = c * 64;
        {
            short tmp[16];
            int grow = m0 + arow;
            if (grow >= NN) {
                #pragma unroll
                for (int j = 0; j < 16; ++j) tmp[j] = 0;
            } else if (c < 2) {
                const short* src = (const short*)xbf + (size_t)grow * 128 + k0 + aseg;
                *(s8v*)tmp = *(const s8v*)src;
                *(s8v*)(tmp + 8) = *(const s8v*)(src + 8);
            } else if (c < 4) {
                const short* src = msgbf + (size_t)grow * 128 + (k0 - 128) + aseg;
                *(s8v*)tmp = *(const s8v*)src;
                *(s8v*)(tmp + 8) = *(const s8v*)(src + 8);
            } else {
                const float* src = gf + aseg;
                #pragma unroll
                for (int q = 0; q < 4; ++q) {
                    float4 v = *reinterpret_cast<const float4*>(src + 4 * q);
                    tmp[4*q+0] = (short)f2b(v.x); tmp[4*q+1] = (short)f2b(v.y);
                    tmp[4*q+2] = (short)f2b(v.z); tmp[4*q+3] = (short)f2b(v.w);
                }
            }
            *(s8v*)&cAs[arow * 72 + aseg] = *(s8v*)tmp;
            *(s8v*)&cAs[arow * 72 + aseg + 8] = *(s8v*)(tmp + 8);
        }
        {
            const short* src = wct + (size_t)wcol * 320 + k0 + wseg;
            #pragma unroll
            for (int j = 0; j < 4; ++j)
                *(s8v*)&cWs[wcol * 72 + wseg + 8 * j] = *(const s8v*)(src + 8 * j);
        }
        __syncthreads();
        const short* ap = cAs + (wv * 16 + fr) * 72 + fc * 8;
        const short* bp = cWs + fr * 72 + fc * 8;
        #pragma unroll
        for (int ks = 0; ks < 2; ++ks) {
            s8v a = *(const s8v*)(ap + ks * 32);
            #pragma unroll
            for (int ct = 0; ct < 8; ++ct) {
                s8v b = *(const s8v*)(bp + ct * 16 * 72 + ks * 32);
                acc[ct] = __builtin_amdgcn_mfma_f32_16x16x32_bf16(a, b, acc[ct], 0, 0, 0);
            }
        }
        __syncthreads();   // staging buffers free after this
    }
    // epilogue: out0 = softplus(acc + bc); write global + LDS A-tile for fused12
    const int rbase = m0 + wv * 16 + fc * 4;
    const int rloc  = wv * 16 + fc * 4;
    #pragma unroll
    for (int ct = 0; ct < 8; ++ct) {
        int col = ct * 16 + fr;
        float bv = bcs[col];
        #pragma unroll
        for (int r = 0; r < 4; ++r) {
            unsigned short q = f2b(softplus_f(acc[ct][r] + bv));
            bool valid = (rbase + r) < NN;
            if (valid) out0bf[(size_t)(rbase + r) * 128 + col] = q;
            As[(rloc + r) * 136 + col] = valid ? (short)q : (short)0;
        }
    }
    // stage W1t
    {
        int col = tid >> 1, seg = (tid & 1) * 64;
        const short* src = w1t + (size_t)col * 128 + seg;
        #pragma unroll
        for (int j = 0; j < 8; ++j)
            *(s8v*)&Ws[col * 136 + seg + 8 * j] = *(const s8v*)(src + 8 * j);
    }
    __syncthreads();
    fused12_tail(smem, w2t, hbf, sout, sums, m0);
}

// ---- kernel: apply block a (inline finalize, 8-copy merge) + fused12 block b -
__global__ __launch_bounds__(256) void apply_f12b_kernel(
    const unsigned short* __restrict__ out0bf,
    const float* __restrict__ sums_a,
    const float* __restrict__ gamma_a, const float* __restrict__ beta_a,
    const short* __restrict__ w1t, const short* __restrict__ w2t,
    const float* __restrict__ b1, const float* __restrict__ b2,
    const float* __restrict__ linW, const float* __restrict__ linb,
    unsigned short* __restrict__ out1bf,
    unsigned short* __restrict__ hbf,     // in: h_a rows (own tile); out: h_b
    float* __restrict__ sout,             // in: s_a rows (own tile); out: s_b
    float* __restrict__ sums_b)
{
    __shared__ __align__(16) char smem[SMEM_BYTES];
    float* ws_  = (float*)(smem);            // 1280
    float* mus_ = (float*)(smem + 5120);     // 1280
    float* ks_  = (float*)(smem + 10240);    // 128
    float* ss_  = (float*)(smem + 10752);    // 640
    short* As   = (short*)(smem);
    short* Ws   = (short*)(smem + 17408);
    float* b1s  = (float*)(smem + 69632);
    float* b2s  = (float*)(smem + 70144);
    float* lws  = (float*)(smem + 70656);
    float* lbs  = (float*)(smem + 76288);

    const int tid = threadIdx.x;
    const int m0 = blockIdx.x * 64;
    if (tid < 128) { b1s[tid] = b1[tid]; b2s[tid] = b2[tid]; }
    for (int i = tid; i < 1280; i += 256) lws[(i / 10) * 11 + (i % 10)] = linW[i];
    if (tid < 10) lbs[tid] = linb[tid];
    const float invn = 1.f / (float)NN;
    for (int idx = tid; idx < 1280; idx += 256) {
        float s1 = 0.f, s2 = 0.f;
        #pragma unroll
        for (int k = 0; k < NCOPY; ++k) {
            s1 += sums_a[(size_t)k * 2560 + idx];
            s2 += sums_a[(size_t)k * 2560 + idx + 1280];
        }
        float mu = s1 * invn;
        float var = s2 * invn - mu * mu;
        float wg = rsqrtf(var + EPSV) * gamma_a[idx];
        ws_[idx] = wg;
        mus_[idx] = mu;
    }
    for (int i = tid; i < 640; i += 256) {
        int n = m0 + i / 10;
        ss_[i] = (n < NN) ? sout[(size_t)n * 10 + i % 10] : 0.f;
    }
    // stage W1t (disjoint LDS region; overlaps nothing in phase A)
    {
        int col = tid >> 1, seg = (tid & 1) * 64;
        const short* src = w1t + (size_t)col * 128 + seg;
        #pragma unroll
        for (int j = 0; j < 8; ++j)
            *(s8v*)&Ws[col * 136 + seg + 8 * j] = *(const s8v*)(src + 8 * j);
    }
    __syncthreads();
    if (tid < 128) {
        float kacc = 0.f;
        #pragma unroll
        for (int g = 0; g < NG; ++g) {
            int idx = g * 128 + tid;
            kacc += beta_a[idx] - mus_[idx] * ws_[idx];
        }
        ks_[tid] = kacc;
    }
    __syncthreads();
    // apply math: out1 = out0 + h + LAM*(h*A + K); keep bf16 vals for A-tile
    const int tc = tid & 31, rg = tid >> 5;
    ushort4 vals[8];
    #pragma unroll
    for (int p = 0; p < 8; ++p) {
        int nl = p * 8 + rg;
        int n = m0 + nl;
        if (n >= NN) { vals[p].x = vals[p].y = vals[p].z = vals[p].w = 0; continue; }
        float A0 = 0.f, A1 = 0.f, A2 = 0.f, A3 = 0.f;
        #pragma unroll
        for (int g = 0; g < 10; ++g) {
            float sv = ss_[nl * 10 + g];
            float4 wv4 = *reinterpret_cast<const float4*>(&ws_[g * 128 + tc * 4]);
            A0 += sv * wv4.x; A1 += sv * wv4.y; A2 += sv * wv4.z; A3 += sv * wv4.w;
        }
        ushort4 hv4 = *reinterpret_cast<const ushort4*>(hbf + (size_t)n * 128 + tc * 4);
        ushort4 ov4 = *reinterpret_cast<const ushort4*>(out0bf + (size_t)n * 128 + tc * 4);
        float h0 = b2f(hv4.x), h1 = b2f(hv4.y), h2 = b2f(hv4.z), h3 = b2f(hv4.w);
        float r0 = b2f(ov4.x) + h0 + LAM * (h0 * A0 + ks_[tc * 4 + 0]);
        float r1 = b2f(ov4.y) + h1 + LAM * (h1 * A1 + ks_[tc * 4 + 1]);
        float r2 = b2f(ov4.z) + h2 + LAM * (h2 * A2 + ks_[tc * 4 + 2]);
        float r3 = b2f(ov4.w) + h3 + LAM * (h3 * A3 + ks_[tc * 4 + 3]);
        ushort4 o;
        o.x = f2b(r0); o.y = f2b(r1); o.z = f2b(r2); o.w = f2b(r3);
        *reinterpret_cast<ushort4*>(out1bf + (size_t)n * 128 + tc * 4) = o;
        vals[p] = o;
    }
    __syncthreads();   // phase-A LDS reads complete
    // write A-tile for fused12_b
    #pragma unroll
    for (int p = 0; p < 8; ++p) {
        int row = p * 8 + rg;
        *reinterpret_cast<ushort4*>(&As[row * 136 + tc * 4]) = vals[p];
    }
    __syncthreads();
    fused12_tail(smem, w2t, hbf, sout, sums_b, m0);
}

// -------------------- apply last: out = out1 + h_b + DGN + initial ------------
__global__ __launch_bounds__(256) void apply_last_kernel(
    const unsigned short* __restrict__ out1bf,
    const unsigned short* __restrict__ hbf,
    const float* __restrict__ s, const float* __restrict__ sums,
    const float* __restrict__ gamma, const float* __restrict__ beta,
    const unsigned short* __restrict__ out0bf,
    float* __restrict__ dstf)
{
    __shared__ __align__(16) float ws_[1280];
    __shared__ float mus_[1280];
    __shared__ float ks_[128];
    __shared__ float ss_[640];
    const int tid = threadIdx.x;
    const int m0 = blockIdx.x * 64;
    const float invn = 1.f / (float)NN;
    for (int idx = tid; idx < 1280; idx += 256) {
        float s1 = 0.f, s2 = 0.f;
        #pragma unroll
        for (int k = 0; k < NCOPY; ++k) {
            s1 += sums[(size_t)k * 2560 + idx];
            s2 += sums[(size_t)k * 2560 + idx + 1280];
        }
        float mu = s1 * invn;
        float var = s2 * invn - mu * mu;
        float wg = rsqrtf(var + EPSV) * gamma[idx];
        ws_[idx] = wg;
        mus_[idx] = mu;
    }
    for (int i = tid; i < 640; i += 256) {
        int n = m0 + i / 10;
        ss_[i] = (n < NN) ? s[(size_t)n * 10 + i % 10] : 0.f;
    }
    __syncthreads();
    if (tid < 128) {
        float kacc = 0.f;
        #pragma unroll
        for (int g = 0; g < NG; ++g) {
            int idx = g * 128 + tid;
            kacc += beta[idx] - mus_[idx] * ws_[idx];
        }
        ks_[tid] = kacc;
    }
    __syncthreads();
    const int tc = tid & 31, rg = tid >> 5;
    #pragma unroll
    for (int p = 0; p < 8; ++p) {
        int nl = p * 8 + rg;
        int n = m0 + nl;
        if (n >= NN) continue;
        float A0 = 0.f, A1 = 0.f, A2 = 0.f, A3 = 0.f;
        #pragma unroll
        for (int g = 0; g < 10; ++g) {
            float sv = ss_[nl * 10 + g];
            float4 wv4 = *reinterpret_cast<const float4*>(&ws_[g * 128 + tc * 4]);
            A0 += sv * wv4.x; A1 += sv * wv4.y; A2 += sv * wv4.z; A3 += sv * wv4.w;
        }
        ushort4 hv4 = *reinterpret_cast<const ushort4*>(hbf + (size_t)n * 128 + tc * 4);
        ushort4 ov4 = *reinterpret_cast<const ushort4*>(out1bf + (size_t)n * 128 + tc * 4);
        ushort4 iv4 = *reinterpret_cast<const ushort4*>(out0bf + (size_t)n * 128 + tc * 4);
        float h0 = b2f(hv4.x), h1 = b2f(hv4.y), h2 = b2f(hv4.z), h3 = b2f(hv4.w);
        float r0 = b2f(ov4.x) + h0 + LAM * (h0 * A0 + ks_[tc * 4 + 0]) + b2f(iv4.x);
        float r1 = b2f(ov4.y) + h1 + LAM * (h1 * A1 + ks_[tc * 4 + 1]) + b2f(iv4.y);
        float r2 = b2f(ov4.z) + h2 + LAM * (h2 * A2 + ks_[tc * 4 + 2]) + b2f(iv4.z);
        float r3 = b2f(ov4.w) + h3 + LAM * (h3 * A3 + ks_[tc * 4 + 3]) + b2f(iv4.w);
        *reinterpret_cast<float4*>(dstf + (size_t)n * 128 + tc * 4) =
            make_float4(r0, r1, r2, r3);
    }
}

// ------------------------------------------------------------------------------
extern "C" void kernel_launch(void* const* d_in, const int* in_sizes, int n_in,
                              void* d_out, int out_size, void* d_ws, size_t ws_size,
                              hipStream_t stream)
{
    const float* x    = (const float*)d_in[0];
    const int*   eidx = (const int*)  d_in[1];
    const float* ef   = (const float*)d_in[2];
    const float* gf   = (const float*)d_in[3];
    const float* Wc   = (const float*)d_in[4];
    const float* bc   = (const float*)d_in[5];

    float* p = (float*)d_ws;
    // zeroed region (single memset): [cnt NN ints][sums_a NCOPY*2560][sums_b ..]
    int*   cnt    = (int*)p;                      p += NN;
    float* sums_a = p;                            p += (size_t)NCOPY * 2560;
    float* sums_b = p;                            p += (size_t)NCOPY * 2560;
    unsigned short* msgbf  = (unsigned short*)p;  p += (size_t)NN * 64;
    unsigned short* out0bf = (unsigned short*)p;  p += (size_t)NN * 64;
    unsigned short* out1bf = (unsigned short*)p;  p += (size_t)NN * 64;
    unsigned short* hbf    = (unsigned short*)p;  p += (size_t)NN * 64;
    unsigned short* xbf    = (unsigned short*)p;  p += (size_t)NN * 64;
    float* sbuf = p;                              p += (size_t)NN * 10;
    short* wct  = (short*)p;                      // 40960 shorts
    short* wts  = wct + 40960;                    // 4*16384 shorts

    // CSR scratch aliased into buffers written later:
    int* off   = (int*)out1bf;           // NN+1  (out1bf written in apply_f12b)
    int* cur   = off + NN + 1;           // NN
    int* bsum  = cur + NN;               // NBLK
    int* eid   = (int*)hbf;              // NE    (hbf written in combine_f12a)

    // zero cnt + both stat-sum regions in one memset
    hipMemsetAsync(cnt, 0, sizeof(int) * (NN + 2 * NCOPY * 2560), stream);

    // histogram + weight prep + x->bf16 (merged, disjoint block ranges)
    hist_prep_kernel<<<EBLOCKS + PBLOCKS + XBLOCKS, 256, 0, stream>>>(
        eidx, cnt, Wc, (const float*)d_in[6], (const float*)d_in[8],
        (const float*)d_in[14], (const float*)d_in[16], wct, wts, x, xbf);

    scan1_kernel<<<NBLK, 256, 0, stream>>>(cnt, bsum);
    scan3_kernel<<<NBLK, 256, 0, stream>>>(cnt, bsum, off, cur);
    fill_kernel <<<EBLOCKS, 256, 0, stream>>>(eidx, cur, eid);
    gather_kernel<<<(NN + 3) / 4, 256, 0, stream>>>(ef, off, eid, (uint4*)msgbf);

    const short* w1ta = wts;
    const short* w2ta = wts + 16384;
    const short* w1tb = wts + 32768;
    const short* w2tb = wts + 49152;

    // combine + block a (writes out0bf, h_a, s_a; atomics sums_a copies)
    combine_f12a_kernel<<<GBLK, 256, 0, stream>>>(
        xbf, (const short*)msgbf, gf, wct, bc,
        w1ta, w2ta, (const float*)d_in[7], (const float*)d_in[9],
        (const float*)d_in[10], (const float*)d_in[11],
        out0bf, hbf, sbuf, sums_a);

    // apply_a + block b (merges sums_a copies; writes out1bf, h_b, s_b)
    apply_f12b_kernel<<<GBLK, 256, 0, stream>>>(
        out0bf, sums_a, (const float*)d_in[12], (const float*)d_in[13],
        w1tb, w2tb, (const float*)d_in[15], (const float*)d_in[17],
        (const float*)d_in[18], (const float*)d_in[19],
        out1bf, hbf, sbuf, sums_b);

    // final apply: d_out = out1 + h_b + DGN_b + initial(out0)
    apply_last_kernel<<<GBLK, 256, 0, stream>>>(
        out1bf, hbf, sbuf, sums_b, (const float*)d_in[20], (const float*)d_in[21],
        out0bf, (float*)d_out);
}